// Round 1
// baseline (2281.363 us; speedup 1.0000x reference)
//
#include <hip/hip_runtime.h>
#include <hip/hip_bf16.h>
#include <math.h>

typedef __bf16 bf16;
typedef __bf16 bf16x8 __attribute__((ext_vector_type(8)));
typedef float  f32x4  __attribute__((ext_vector_type(4)));

#define DMODEL 1536
#define NHEADS 12
#define HD 128
#define HDH 64

// ---------------- block reduction (block = 256) ----------------
__device__ inline void block_reduce2(float& a, float& b) {
  __shared__ float sa[4], sb[4];
  #pragma unroll
  for (int off = 32; off; off >>= 1) {
    a += __shfl_xor(a, off);
    b += __shfl_xor(b, off);
  }
  int w = threadIdx.x >> 6;
  if ((threadIdx.x & 63) == 0) { sa[w] = a; sb[w] = b; }
  __syncthreads();
  a = sa[0] + sa[1] + sa[2] + sa[3];
  b = sb[0] + sb[1] + sb[2] + sb[3];
  __syncthreads();
}

// ---------------- LayerNorm (+AdaLN modulate or affine) ----------------
// mode 0: y = LN(x)*(1+scalevec)+shiftvec, scale/shift = sst[j]+temb[f][j]
// mode 1: y = LN(x)*g + b
__global__ __launch_bounds__(256)
void ln_kernel(const float* __restrict__ X, bf16* __restrict__ Y,
               const float* __restrict__ sst, const float* __restrict__ temb,
               const float* __restrict__ g, const float* __restrict__ bvec,
               int jshift, int jscale, int FS, int mode)
{
  int row = blockIdx.x;
  const float* x = X + (size_t)row * DMODEL;
  float v[6];
  float s1 = 0.f, s2 = 0.f;
  #pragma unroll
  for (int i = 0; i < 6; i++) {
    float t = x[threadIdx.x + i * 256];
    v[i] = t; s1 += t; s2 += t * t;
  }
  block_reduce2(s1, s2);
  float mean = s1 * (1.f / DMODEL);
  float var  = s2 * (1.f / DMODEL) - mean * mean;
  float rs = rsqrtf(var + 1e-6f);
  int f = row / FS;
  bf16* y = Y + (size_t)row * DMODEL;
  #pragma unroll
  for (int i = 0; i < 6; i++) {
    int d = threadIdx.x + i * 256;
    float t = (v[i] - mean) * rs;
    float o;
    if (mode == 0) {
      float sc = sst[jscale * DMODEL + d] + temb[(f * 6 + jscale) * DMODEL + d];
      float sh = sst[jshift * DMODEL + d] + temb[(f * 6 + jshift) * DMODEL + d];
      o = t * (1.f + sc) + sh;
    } else {
      o = t * g[d] + bvec[d];
    }
    y[d] = (bf16)o;
  }
}

// ---------------- RMSNorm (+ optional interleaved RoPE) ----------------
__global__ __launch_bounds__(256)
void rms_rope_kernel(const float* __restrict__ X, bf16* __restrict__ Y,
                     const float* __restrict__ w,
                     const float* __restrict__ cosb, const float* __restrict__ sinb,
                     int dorope)
{
  int row = blockIdx.x;
  const float* x = X + (size_t)row * DMODEL;
  float v[6];
  float s2 = 0.f, dummy = 0.f;
  #pragma unroll
  for (int i = 0; i < 6; i++) {
    float t = x[threadIdx.x + i * 256];
    v[i] = t; s2 += t * t;
  }
  block_reduce2(s2, dummy);
  float rs = rsqrtf(s2 * (1.f / DMODEL) + 1e-6f);
  bf16* y = Y + (size_t)row * DMODEL;
  if (dorope) {
    #pragma unroll
    for (int i = 0; i < 3; i++) {
      int p = threadIdx.x + i * 256;     // pair index 0..767
      int d0 = 2 * p, d1 = 2 * p + 1;
      float y0 = x[d0] * rs * w[d0];
      float y1 = x[d1] * rs * w[d1];
      int ih = p & 63;                    // pair-in-head (hd/2 = 64)
      float c = cosb[(size_t)row * HDH + ih];
      float s = sinb[(size_t)row * HDH + ih];
      y[d0] = (bf16)(y0 * c - y1 * s);
      y[d1] = (bf16)(y0 * s + y1 * c);
    }
  } else {
    #pragma unroll
    for (int i = 0; i < 6; i++) {
      int d = threadIdx.x + i * 256;
      y[d] = (bf16)(v[i] * rs * w[d]);
    }
  }
}

// ---------------- GEMM: C[MxN] = A(bf16,MxK) @ W(fp32,KxN) + bias ----------------
// act: 0 = none, 1 = gelu(tanh). Writes Cf (fp32) if non-null else Cb (bf16).
__global__ __launch_bounds__(256)
void gemm_kernel(const bf16* __restrict__ A, const float* __restrict__ W,
                 const float* __restrict__ bias, float* __restrict__ Cf,
                 bf16* __restrict__ Cb, int M, int N, int K, int act)
{
  __shared__ bf16 As[64][40];
  __shared__ bf16 Bs[64][40];   // transposed: Bs[n][k]
  int bm = blockIdx.x * 64;
  int bn = blockIdx.y * 64;
  int tid = threadIdx.x;
  int lane = tid & 63;
  int w = tid >> 6;
  int wm = w >> 1, wn = w & 1;
  int l16 = lane & 15, quad = lane >> 4;

  f32x4 acc[2][2] = {};
  int am = tid >> 2;            // 0..63
  int ak = (tid & 3) * 8;       // 0,8,16,24
  int bk = tid >> 3;            // 0..31
  int bn8 = (tid & 7) * 8;      // 0..56

  const bf16* Arow = A + (size_t)(bm + am) * K;
  bool avalid = (bm + am) < M;

  for (int k0 = 0; k0 < K; k0 += 32) {
    if (avalid) {
      *(bf16x8*)&As[am][ak] = *(const bf16x8*)&Arow[k0 + ak];
    } else {
      bf16x8 z = {};
      *(bf16x8*)&As[am][ak] = z;
    }
    const float* wrow = W + (size_t)(k0 + bk) * N + bn + bn8;
    float4 w0 = *(const float4*)wrow;
    float4 w1 = *(const float4*)(wrow + 4);
    Bs[bn8 + 0][bk] = (bf16)w0.x; Bs[bn8 + 1][bk] = (bf16)w0.y;
    Bs[bn8 + 2][bk] = (bf16)w0.z; Bs[bn8 + 3][bk] = (bf16)w0.w;
    Bs[bn8 + 4][bk] = (bf16)w1.x; Bs[bn8 + 5][bk] = (bf16)w1.y;
    Bs[bn8 + 6][bk] = (bf16)w1.z; Bs[bn8 + 7][bk] = (bf16)w1.w;
    __syncthreads();
    bf16x8 af[2], bfr[2];
    #pragma unroll
    for (int mi = 0; mi < 2; mi++)
      af[mi] = *(const bf16x8*)&As[wm * 32 + mi * 16 + l16][quad * 8];
    #pragma unroll
    for (int ni = 0; ni < 2; ni++)
      bfr[ni] = *(const bf16x8*)&Bs[wn * 32 + ni * 16 + l16][quad * 8];
    #pragma unroll
    for (int mi = 0; mi < 2; mi++)
      #pragma unroll
      for (int ni = 0; ni < 2; ni++)
        acc[mi][ni] = __builtin_amdgcn_mfma_f32_16x16x32_bf16(af[mi], bfr[ni], acc[mi][ni], 0, 0, 0);
    __syncthreads();
  }
  #pragma unroll
  for (int mi = 0; mi < 2; mi++) {
    #pragma unroll
    for (int ni = 0; ni < 2; ni++) {
      #pragma unroll
      for (int r = 0; r < 4; r++) {
        int m = bm + wm * 32 + mi * 16 + quad * 4 + r;
        int n = bn + wn * 32 + ni * 16 + l16;
        if (m < M) {
          float val = acc[mi][ni][r] + bias[n];
          if (act == 1) {
            float x3 = val * val * val;
            float t = tanhf(0.7978845608028654f * (val + 0.044715f * x3));
            val = 0.5f * val * (1.f + t);
          }
          if (Cf) Cf[(size_t)m * N + n] = val;
          else    Cb[(size_t)m * N + n] = (bf16)val;
        }
      }
    }
  }
}

// ---------------- transpose V (Lx1536 -> 1536xL) ----------------
__global__ __launch_bounds__(256)
void transpose_kernel(const bf16* __restrict__ V, bf16* __restrict__ Vt, int L)
{
  __shared__ bf16 T[64][65];
  int l0 = blockIdx.x * 64, n0 = blockIdx.y * 64;
  int tid = threadIdx.x;
  int r = tid >> 2;            // 0..63
  int c8 = (tid & 3) * 16;     // 0,16,32,48
  if (l0 + r < L) {
    #pragma unroll
    for (int i = 0; i < 16; i++)
      T[r][c8 + i] = V[(size_t)(l0 + r) * DMODEL + n0 + c8 + i];
  } else {
    #pragma unroll
    for (int i = 0; i < 16; i++) T[r][c8 + i] = (bf16)0.f;
  }
  __syncthreads();
  #pragma unroll
  for (int i = 0; i < 16; i++) {
    int l = l0 + c8 + i;
    if (l < L) Vt[(size_t)(n0 + r) * L + l] = T[c8 + i][r];
  }
}

// ---------------- MFMA flash attention ----------------
// Q,K: (Lq,12,128)/(Lk,12,128) bf16 row-major; Vt: (1536, Lk) bf16; O: (Lq,1536)
__global__ __launch_bounds__(256)
void flash_kernel(const bf16* __restrict__ Q, const bf16* __restrict__ K,
                  const bf16* __restrict__ Vt, bf16* __restrict__ O,
                  int Lq, int Lk, int FS, int causal)
{
  __shared__ bf16 Pl[4][16][40];
  int w = threadIdx.x >> 6;
  int lane = threadIdx.x & 63;
  int l16 = lane & 15, quad = lane >> 4;
  int nqt = Lq >> 4;
  int wid = blockIdx.x * 4 + w;
  if (wid >= NHEADS * nqt) return;
  int h = wid / nqt;
  int q0 = (wid % nqt) << 4;
  const float scale = 0.08838834764831845f; // 1/sqrt(128)

  bf16x8 qf[4];
  const bf16* qbase = Q + (size_t)(q0 + l16) * DMODEL + h * HD + quad * 8;
  #pragma unroll
  for (int dc = 0; dc < 4; dc++)
    qf[dc] = *(const bf16x8*)(qbase + dc * 32);

  f32x4 acc_o[8] = {};
  float m_i[4], l_i[4];
  #pragma unroll
  for (int r = 0; r < 4; r++) { m_i[r] = -1e30f; l_i[r] = 0.f; }
  int kvrow[4];
  int kv_hi;
  if (causal) {
    #pragma unroll
    for (int r = 0; r < 4; r++) kvrow[r] = ((q0 + quad * 4 + r) / FS + 1) * FS;
    kv_hi = ((q0 + 15) / FS + 1) * FS;
    if (kv_hi > Lk) kv_hi = Lk;
  } else kv_hi = Lk;

  for (int kb = 0; kb < kv_hi; kb += 32) {
    f32x4 s[2] = {};
    #pragma unroll
    for (int nk = 0; nk < 2; nk++) {
      const bf16* kbase = K + (size_t)(kb + nk * 16 + l16) * DMODEL + h * HD + quad * 8;
      #pragma unroll
      for (int dc = 0; dc < 4; dc++) {
        bf16x8 kf = *(const bf16x8*)(kbase + dc * 32);
        s[nk] = __builtin_amdgcn_mfma_f32_16x16x32_bf16(qf[dc], kf, s[nk], 0, 0, 0);
      }
    }
    float p[2][4];
    #pragma unroll
    for (int nk = 0; nk < 2; nk++) {
      int kj = kb + nk * 16 + l16;
      #pragma unroll
      for (int r = 0; r < 4; r++) {
        float sv = s[nk][r] * scale;
        if (causal && kj >= kvrow[r]) sv = -1e30f;
        p[nk][r] = sv;
      }
    }
    #pragma unroll
    for (int r = 0; r < 4; r++) {
      float bm = fmaxf(p[0][r], p[1][r]);
      #pragma unroll
      for (int off = 8; off; off >>= 1) bm = fmaxf(bm, __shfl_xor(bm, off));
      float mn = fmaxf(m_i[r], bm);
      float alpha = __expf(m_i[r] - mn);
      m_i[r] = mn;
      float p0 = __expf(p[0][r] - mn);
      float p1 = __expf(p[1][r] - mn);
      p[0][r] = p0; p[1][r] = p1;
      float ps = p0 + p1;
      #pragma unroll
      for (int off = 8; off; off >>= 1) ps += __shfl_xor(ps, off);
      l_i[r] = l_i[r] * alpha + ps;
      #pragma unroll
      for (int t = 0; t < 8; t++) acc_o[t][r] *= alpha;
    }
    #pragma unroll
    for (int nk = 0; nk < 2; nk++)
      #pragma unroll
      for (int r = 0; r < 4; r++)
        Pl[w][quad * 4 + r][nk * 16 + l16] = (bf16)p[nk][r];
    __threadfence_block();   // wave-private LDS; DS pipe is in-order per wave
    bf16x8 pf = *(const bf16x8*)&Pl[w][l16][quad * 8];
    #pragma unroll
    for (int t = 0; t < 8; t++) {
      const bf16* vbase = Vt + (size_t)(h * HD + t * 16 + l16) * Lk + kb + quad * 8;
      bf16x8 vf = *(const bf16x8*)vbase;
      acc_o[t] = __builtin_amdgcn_mfma_f32_16x16x32_bf16(pf, vf, acc_o[t], 0, 0, 0);
    }
  }
  #pragma unroll
  for (int r = 0; r < 4; r++) {
    float inv = 1.f / l_i[r];
    bf16* obase = O + (size_t)(q0 + quad * 4 + r) * DMODEL + h * HD;
    #pragma unroll
    for (int t = 0; t < 8; t++)
      obase[t * 16 + l16] = (bf16)(acc_o[t][r] * inv);
  }
}

// ---------------- elementwise ----------------
__global__ __launch_bounds__(256)
void modresid_kernel(const float* __restrict__ base, const float* __restrict__ xin,
                     float* __restrict__ out,
                     const float* __restrict__ sst, const float* __restrict__ temb,
                     int jg, int FS, long long total)
{
  long long i = (long long)blockIdx.x * 256 + threadIdx.x;
  if (i >= total) return;
  int d = (int)(i % DMODEL);
  int f = (int)((i / DMODEL) / FS);
  float g = sst[jg * DMODEL + d] + temb[(f * 6 + jg) * DMODEL + d];
  out[i] = base[i] + xin[i] * g;
}

__global__ __launch_bounds__(256)
void add_kernel(float* __restrict__ h, const float* __restrict__ x, long long total)
{
  long long i = (long long)blockIdx.x * 256 + threadIdx.x;
  if (i < total) h[i] += x[i];
}

__global__ __launch_bounds__(256)
void cast_kernel(const float* __restrict__ x, bf16* __restrict__ y, long long total)
{
  long long i = (long long)blockIdx.x * 256 + threadIdx.x;
  if (i < total) y[i] = (bf16)x[i];
}

// ---------------- orchestration ----------------
extern "C" void kernel_launch(void* const* d_in, const int* in_sizes, int n_in,
                              void* d_out, int out_size, void* d_ws, size_t ws_size,
                              hipStream_t stream)
{
  const float* hs   = (const float*)d_in[0];
  const float* enc  = (const float*)d_in[1];
  const float* temb = (const float*)d_in[2];
  const float* cosb = (const float*)d_in[3];
  const float* sinb = (const float*)d_in[4];
  const float* sst  = (const float*)d_in[6];
  const float* wq = (const float*)d_in[7];
  const float* wk = (const float*)d_in[8];
  const float* wv = (const float*)d_in[9];
  const float* wo = (const float*)d_in[10];
  const float* bq = (const float*)d_in[11];
  const float* bk = (const float*)d_in[12];
  const float* bv = (const float*)d_in[13];
  const float* bo = (const float*)d_in[14];
  const float* nq_w = (const float*)d_in[15];
  const float* nk_w = (const float*)d_in[16];
  const float* ln2_g = (const float*)d_in[17];
  const float* ln2_b = (const float*)d_in[18];
  const float* cwq = (const float*)d_in[19];
  const float* cwk = (const float*)d_in[20];
  const float* cwv = (const float*)d_in[21];
  const float* cwo = (const float*)d_in[22];
  const float* cbq = (const float*)d_in[23];
  const float* cbk = (const float*)d_in[24];
  const float* cbv = (const float*)d_in[25];
  const float* cbo = (const float*)d_in[26];
  const float* cnq_w = (const float*)d_in[27];
  const float* cnk_w = (const float*)d_in[28];
  const float* w1 = (const float*)d_in[29];
  const float* b1 = (const float*)d_in[30];
  const float* w2 = (const float*)d_in[31];
  const float* b2 = (const float*)d_in[32];

  int L  = in_sizes[0] / DMODEL;
  int LC = in_sizes[1] / DMODEL;
  int F  = in_sizes[2] / (6 * DMODEL);
  int FS = L / F;
  int FF = in_sizes[30];
  long long LD = (long long)L * DMODEL;
  float* outp = (float*)d_out;

  char* p = (char*)d_ws;
  auto alloc = [&](size_t bytes) -> char* {
    char* r = p; p += (bytes + 255) & ~(size_t)255; return r;
  };
  bf16* nh   = (bf16*)alloc((size_t)LD * 2);
  bf16* qb   = (bf16*)alloc((size_t)LD * 2);
  bf16* kb   = (bf16*)alloc((size_t)LD * 2);
  bf16* vb   = (bf16*)alloc((size_t)LD * 2);
  bf16* ab   = (bf16*)alloc((size_t)LD * 2);
  bf16* vtb  = (bf16*)alloc((size_t)LD * 2);
  bf16* vtc  = (bf16*)alloc((size_t)LC * DMODEL * 2);
  bf16* encb = (bf16*)alloc((size_t)LC * DMODEL * 2);
  bf16* ffb  = (bf16*)alloc((size_t)L * FF * 2);
  float* Cf  = (float*)alloc((size_t)LD * 4);
  float* hbuf = (float*)alloc((size_t)LD * 4);
  (void)ws_size; (void)n_in; (void)out_size;

  dim3 gD((L + 63) / 64, DMODEL / 64);       // M=L, N=1536
  dim3 gC((LC + 63) / 64, DMODEL / 64);      // M=LC, N=1536
  dim3 gF1((L + 63) / 64, FF / 64);          // M=L, N=FF
  int ewg = (int)((LD + 255) / 256);
  int flashg = (NHEADS * (L >> 4) + 3) / 4;

  // 1) AdaLN-modulated LN of hidden
  ln_kernel<<<L, 256, 0, stream>>>(hs, nh, sst, temb, nullptr, nullptr, 0, 1, FS, 0);
  // 2) q/k/v projections
  gemm_kernel<<<gD, 256, 0, stream>>>(nh, wq, bq, Cf, nullptr, L, DMODEL, DMODEL, 0);
  rms_rope_kernel<<<L, 256, 0, stream>>>(Cf, qb, nq_w, cosb, sinb, 1);
  gemm_kernel<<<gD, 256, 0, stream>>>(nh, wk, bk, Cf, nullptr, L, DMODEL, DMODEL, 0);
  rms_rope_kernel<<<L, 256, 0, stream>>>(Cf, kb, nk_w, cosb, sinb, 1);
  gemm_kernel<<<gD, 256, 0, stream>>>(nh, wv, bv, nullptr, vb, L, DMODEL, DMODEL, 0);
  transpose_kernel<<<dim3((L + 63) / 64, DMODEL / 64), 256, 0, stream>>>(vb, vtb, L);
  // 3) self attention (block-causal)
  flash_kernel<<<flashg, 256, 0, stream>>>(qb, kb, vtb, ab, L, L, FS, 1);
  gemm_kernel<<<gD, 256, 0, stream>>>(ab, wo, bo, Cf, nullptr, L, DMODEL, DMODEL, 0);
  modresid_kernel<<<ewg, 256, 0, stream>>>(hs, Cf, hbuf, sst, temb, 2, FS, LD);
  // 4) cross attention
  ln_kernel<<<L, 256, 0, stream>>>(hbuf, nh, nullptr, nullptr, ln2_g, ln2_b, 0, 0, FS, 1);
  gemm_kernel<<<gD, 256, 0, stream>>>(nh, cwq, cbq, Cf, nullptr, L, DMODEL, DMODEL, 0);
  rms_rope_kernel<<<L, 256, 0, stream>>>(Cf, qb, cnq_w, nullptr, nullptr, 0);
  cast_kernel<<<(int)(((long long)LC * DMODEL + 255) / 256), 256, 0, stream>>>(enc, encb, (long long)LC * DMODEL);
  gemm_kernel<<<gC, 256, 0, stream>>>(encb, cwk, cbk, Cf, nullptr, LC, DMODEL, DMODEL, 0);
  rms_rope_kernel<<<LC, 256, 0, stream>>>(Cf, kb, cnk_w, nullptr, nullptr, 0);
  gemm_kernel<<<gC, 256, 0, stream>>>(encb, cwv, cbv, nullptr, vb, LC, DMODEL, DMODEL, 0);
  transpose_kernel<<<dim3((LC + 63) / 64, DMODEL / 64), 256, 0, stream>>>(vb, vtc, LC);
  flash_kernel<<<flashg, 256, 0, stream>>>(qb, kb, vtc, ab, L, LC, FS, 0);
  gemm_kernel<<<gD, 256, 0, stream>>>(ab, cwo, cbo, Cf, nullptr, L, DMODEL, DMODEL, 0);
  add_kernel<<<ewg, 256, 0, stream>>>(hbuf, Cf, LD);
  // 5) FFN with AdaLN modulate + gated residual
  ln_kernel<<<L, 256, 0, stream>>>(hbuf, nh, sst, temb, nullptr, nullptr, 3, 4, FS, 0);
  gemm_kernel<<<gF1, 256, 0, stream>>>(nh, w1, b1, nullptr, ffb, L, FF, DMODEL, 1);
  gemm_kernel<<<gD, 256, 0, stream>>>(ffb, w2, b2, Cf, nullptr, L, DMODEL, FF, 0);
  modresid_kernel<<<ewg, 256, 0, stream>>>(hbuf, Cf, outp, sst, temb, 5, FS, LD);
}

// Round 2
// 1637.679 us; speedup vs baseline: 1.3930x; 1.3930x over previous
//
#include <hip/hip_runtime.h>
#include <hip/hip_bf16.h>
#include <math.h>

typedef __bf16 bf16;
typedef __bf16 bf16x8 __attribute__((ext_vector_type(8)));
typedef float  f32x4  __attribute__((ext_vector_type(4)));
typedef unsigned int u32;

#define DMODEL 1536
#define NHEADS 12
#define HD 128
#define HDH 64

__device__ __forceinline__ void async16(const void* g, void* l) {
  __builtin_amdgcn_global_load_lds((const __attribute__((address_space(1))) u32*)g,
                                   (__attribute__((address_space(3))) u32*)l, 16, 0, 0);
}

// ---------------- block reduction (block = 256) ----------------
__device__ inline void block_reduce2(float& a, float& b) {
  __shared__ float sa[4], sb[4];
  #pragma unroll
  for (int off = 32; off; off >>= 1) {
    a += __shfl_xor(a, off);
    b += __shfl_xor(b, off);
  }
  int w = threadIdx.x >> 6;
  if ((threadIdx.x & 63) == 0) { sa[w] = a; sb[w] = b; }
  __syncthreads();
  a = sa[0] + sa[1] + sa[2] + sa[3];
  b = sb[0] + sb[1] + sb[2] + sb[3];
  __syncthreads();
}

// ---------------- LayerNorm (+AdaLN modulate or affine) ----------------
__global__ __launch_bounds__(256)
void ln_kernel(const float* __restrict__ X, bf16* __restrict__ Y,
               const float* __restrict__ sst, const float* __restrict__ temb,
               const float* __restrict__ g, const float* __restrict__ bvec,
               int jshift, int jscale, int FS, int mode)
{
  int row = blockIdx.x;
  const float* x = X + (size_t)row * DMODEL;
  float v[6];
  float s1 = 0.f, s2 = 0.f;
  #pragma unroll
  for (int i = 0; i < 6; i++) {
    float t = x[threadIdx.x + i * 256];
    v[i] = t; s1 += t; s2 += t * t;
  }
  block_reduce2(s1, s2);
  float mean = s1 * (1.f / DMODEL);
  float var  = s2 * (1.f / DMODEL) - mean * mean;
  float rs = rsqrtf(var + 1e-6f);
  int f = row / FS;
  bf16* y = Y + (size_t)row * DMODEL;
  #pragma unroll
  for (int i = 0; i < 6; i++) {
    int d = threadIdx.x + i * 256;
    float t = (v[i] - mean) * rs;
    float o;
    if (mode == 0) {
      float sc = sst[jscale * DMODEL + d] + temb[(f * 6 + jscale) * DMODEL + d];
      float sh = sst[jshift * DMODEL + d] + temb[(f * 6 + jshift) * DMODEL + d];
      o = t * (1.f + sc) + sh;
    } else {
      o = t * g[d] + bvec[d];
    }
    y[d] = (bf16)o;
  }
}

// ---------------- RMSNorm (+ optional interleaved RoPE) ----------------
__global__ __launch_bounds__(256)
void rms_rope_kernel(const float* __restrict__ X, bf16* __restrict__ Y,
                     const float* __restrict__ w,
                     const float* __restrict__ cosb, const float* __restrict__ sinb,
                     int dorope)
{
  int row = blockIdx.x;
  const float* x = X + (size_t)row * DMODEL;
  float v[6];
  float s2 = 0.f, dummy = 0.f;
  #pragma unroll
  for (int i = 0; i < 6; i++) {
    float t = x[threadIdx.x + i * 256];
    v[i] = t; s2 += t * t;
  }
  block_reduce2(s2, dummy);
  float rs = rsqrtf(s2 * (1.f / DMODEL) + 1e-6f);
  bf16* y = Y + (size_t)row * DMODEL;
  if (dorope) {
    #pragma unroll
    for (int i = 0; i < 3; i++) {
      int p = threadIdx.x + i * 256;
      int d0 = 2 * p, d1 = 2 * p + 1;
      float y0 = x[d0] * rs * w[d0];
      float y1 = x[d1] * rs * w[d1];
      int ih = p & 63;
      float c = cosb[(size_t)row * HDH + ih];
      float s = sinb[(size_t)row * HDH + ih];
      y[d0] = (bf16)(y0 * c - y1 * s);
      y[d1] = (bf16)(y0 * s + y1 * c);
    }
  } else {
    #pragma unroll
    for (int i = 0; i < 6; i++) {
      int d = threadIdx.x + i * 256;
      y[d] = (bf16)(v[i] * rs * w[d]);
    }
  }
}

// ---------------- weight transpose+cast: W (K,N) fp32 -> Wt (N,K) bf16 ----------------
__global__ __launch_bounds__(256)
void wt_kernel(const float* __restrict__ W, bf16* __restrict__ Wt, int K, int N)
{
  __shared__ float T[32][33];
  int k0 = blockIdx.x * 32, n0 = blockIdx.y * 32;
  int tx = threadIdx.x & 31, ty = threadIdx.x >> 5;   // ty 0..7
  #pragma unroll
  for (int i = 0; i < 4; i++)
    T[ty + 8 * i][tx] = W[(size_t)(k0 + ty + 8 * i) * N + n0 + tx];
  __syncthreads();
  #pragma unroll
  for (int i = 0; i < 4; i++)
    Wt[(size_t)(n0 + ty + 8 * i) * K + k0 + tx] = (bf16)T[tx][ty + 8 * i];
}

// ---------------- GEMM m97-style: C[MxN] = A(bf16 MxK) @ Bt(bf16 NxK)^T + bias ----------------
// 128x128 tile, BK=32, global_load_lds 16B staging, 4 waves of 4x4 16x16x32 MFMA.
__global__ __launch_bounds__(256)
void gemm_bt(const bf16* __restrict__ A, const bf16* __restrict__ Bt,
             const float* __restrict__ bias, float* __restrict__ Cf,
             bf16* __restrict__ Cb, int M, int N, int K, int act)
{
  __shared__ bf16 As[128 * 32];
  __shared__ bf16 Bs[128 * 32];
  int tid = threadIdx.x, lane = tid & 63, w = tid >> 6;
  int wm = w >> 1, wn = w & 1;
  int l16 = lane & 15, quad = lane >> 4;
  int bm = blockIdx.x * 128, bn = blockIdx.y * 128;

  int rl = lane >> 2;             // 0..15
  int kk = (lane & 3) * 8;        // 0,8,16,24
  int r0 = (2 * w) * 16 + rl, r1 = (2 * w + 1) * 16 + rl;
  int am0 = bm + r0; if (am0 > M - 1) am0 = M - 1;
  int am1 = bm + r1; if (am1 > M - 1) am1 = M - 1;
  const bf16* a0 = A + (size_t)am0 * K + kk;
  const bf16* a1 = A + (size_t)am1 * K + kk;
  const bf16* b0 = Bt + (size_t)(bn + r0) * K + kk;
  const bf16* b1 = Bt + (size_t)(bn + r1) * K + kk;
  bf16* lA0 = As + (2 * w) * 512; bf16* lA1 = As + (2 * w + 1) * 512;
  bf16* lB0 = Bs + (2 * w) * 512; bf16* lB1 = Bs + (2 * w + 1) * 512;

  f32x4 acc[4][4] = {};
  for (int k0 = 0; k0 < K; k0 += 32) {
    async16(a0 + k0, lA0);
    async16(a1 + k0, lA1);
    async16(b0 + k0, lB0);
    async16(b1 + k0, lB1);
    __syncthreads();
    bf16x8 af[4], bfv[4];
    #pragma unroll
    for (int mi = 0; mi < 4; mi++)
      af[mi] = *(const bf16x8*)&As[(wm * 64 + mi * 16 + l16) * 32 + quad * 8];
    #pragma unroll
    for (int ni = 0; ni < 4; ni++)
      bfv[ni] = *(const bf16x8*)&Bs[(wn * 64 + ni * 16 + l16) * 32 + quad * 8];
    #pragma unroll
    for (int mi = 0; mi < 4; mi++)
      #pragma unroll
      for (int ni = 0; ni < 4; ni++)
        acc[mi][ni] = __builtin_amdgcn_mfma_f32_16x16x32_bf16(af[mi], bfv[ni], acc[mi][ni], 0, 0, 0);
    __syncthreads();
  }
  #pragma unroll
  for (int mi = 0; mi < 4; mi++) {
    #pragma unroll
    for (int r = 0; r < 4; r++) {
      int m = bm + wm * 64 + mi * 16 + quad * 4 + r;
      if (m < M) {
        #pragma unroll
        for (int ni = 0; ni < 4; ni++) {
          int n = bn + wn * 64 + ni * 16 + l16;
          float val = acc[mi][ni][r] + bias[n];
          if (act == 1) {
            float u = val + 0.044715f * val * val * val;
            float z = 1.5957691216057308f * u;
            val = val / (1.f + __expf(-z));   // == 0.5*val*(1+tanh(0.79788456*u))
          }
          if (Cf) Cf[(size_t)m * N + n] = val;
          else    Cb[(size_t)m * N + n] = (bf16)val;
        }
      }
    }
  }
}

// ---------------- transpose V (Lx1536 -> 1536xL) ----------------
__global__ __launch_bounds__(256)
void transpose_kernel(const bf16* __restrict__ V, bf16* __restrict__ Vt, int L)
{
  __shared__ bf16 T[64][65];
  int l0 = blockIdx.x * 64, n0 = blockIdx.y * 64;
  int tid = threadIdx.x;
  int r = tid >> 2;
  int c8 = (tid & 3) * 16;
  if (l0 + r < L) {
    #pragma unroll
    for (int i = 0; i < 16; i++)
      T[r][c8 + i] = V[(size_t)(l0 + r) * DMODEL + n0 + c8 + i];
  } else {
    #pragma unroll
    for (int i = 0; i < 16; i++) T[r][c8 + i] = (bf16)0.f;
  }
  __syncthreads();
  #pragma unroll
  for (int i = 0; i < 16; i++) {
    int l = l0 + c8 + i;
    if (l < L) Vt[(size_t)(n0 + r) * L + l] = T[c8 + i][r];
  }
}

// ---------------- MFMA flash attention ----------------
__global__ __launch_bounds__(256)
void flash_kernel(const bf16* __restrict__ Q, const bf16* __restrict__ K,
                  const bf16* __restrict__ Vt, bf16* __restrict__ O,
                  int Lq, int Lk, int FS, int causal)
{
  __shared__ bf16 Pl[4][16][40];
  int w = threadIdx.x >> 6;
  int lane = threadIdx.x & 63;
  int l16 = lane & 15, quad = lane >> 4;
  int nqt = Lq >> 4;
  int wid = blockIdx.x * 4 + w;
  if (wid >= NHEADS * nqt) return;
  int h = wid / nqt;
  int q0 = (wid % nqt) << 4;
  const float scale = 0.08838834764831845f;

  bf16x8 qf[4];
  const bf16* qbase = Q + (size_t)(q0 + l16) * DMODEL + h * HD + quad * 8;
  #pragma unroll
  for (int dc = 0; dc < 4; dc++)
    qf[dc] = *(const bf16x8*)(qbase + dc * 32);

  f32x4 acc_o[8] = {};
  float m_i[4], l_i[4];
  #pragma unroll
  for (int r = 0; r < 4; r++) { m_i[r] = -1e30f; l_i[r] = 0.f; }
  int kvrow[4];
  int kv_hi;
  if (causal) {
    #pragma unroll
    for (int r = 0; r < 4; r++) kvrow[r] = ((q0 + quad * 4 + r) / FS + 1) * FS;
    kv_hi = ((q0 + 15) / FS + 1) * FS;
    if (kv_hi > Lk) kv_hi = Lk;
  } else kv_hi = Lk;

  for (int kb = 0; kb < kv_hi; kb += 32) {
    f32x4 s[2] = {};
    #pragma unroll
    for (int nk = 0; nk < 2; nk++) {
      const bf16* kbase = K + (size_t)(kb + nk * 16 + l16) * DMODEL + h * HD + quad * 8;
      #pragma unroll
      for (int dc = 0; dc < 4; dc++) {
        bf16x8 kf = *(const bf16x8*)(kbase + dc * 32);
        s[nk] = __builtin_amdgcn_mfma_f32_16x16x32_bf16(qf[dc], kf, s[nk], 0, 0, 0);
      }
    }
    float p[2][4];
    #pragma unroll
    for (int nk = 0; nk < 2; nk++) {
      int kj = kb + nk * 16 + l16;
      #pragma unroll
      for (int r = 0; r < 4; r++) {
        float sv = s[nk][r] * scale;
        if (causal && kj >= kvrow[r]) sv = -1e30f;
        p[nk][r] = sv;
      }
    }
    #pragma unroll
    for (int r = 0; r < 4; r++) {
      float bm = fmaxf(p[0][r], p[1][r]);
      #pragma unroll
      for (int off = 8; off; off >>= 1) bm = fmaxf(bm, __shfl_xor(bm, off));
      float mn = fmaxf(m_i[r], bm);
      float alpha = __expf(m_i[r] - mn);
      m_i[r] = mn;
      float p0 = __expf(p[0][r] - mn);
      float p1 = __expf(p[1][r] - mn);
      p[0][r] = p0; p[1][r] = p1;
      float ps = p0 + p1;
      #pragma unroll
      for (int off = 8; off; off >>= 1) ps += __shfl_xor(ps, off);
      l_i[r] = l_i[r] * alpha + ps;
      #pragma unroll
      for (int t = 0; t < 8; t++) acc_o[t][r] *= alpha;
    }
    #pragma unroll
    for (int nk = 0; nk < 2; nk++)
      #pragma unroll
      for (int r = 0; r < 4; r++)
        Pl[w][quad * 4 + r][nk * 16 + l16] = (bf16)p[nk][r];
    __threadfence_block();
    bf16x8 pf = *(const bf16x8*)&Pl[w][l16][quad * 8];
    #pragma unroll
    for (int t = 0; t < 8; t++) {
      const bf16* vbase = Vt + (size_t)(h * HD + t * 16 + l16) * Lk + kb + quad * 8;
      bf16x8 vf = *(const bf16x8*)vbase;
      acc_o[t] = __builtin_amdgcn_mfma_f32_16x16x32_bf16(pf, vf, acc_o[t], 0, 0, 0);
    }
  }
  #pragma unroll
  for (int r = 0; r < 4; r++) {
    float inv = 1.f / l_i[r];
    bf16* obase = O + (size_t)(q0 + quad * 4 + r) * DMODEL + h * HD;
    #pragma unroll
    for (int t = 0; t < 8; t++)
      obase[t * 16 + l16] = (bf16)(acc_o[t][r] * inv);
  }
}

// ---------------- elementwise ----------------
__global__ __launch_bounds__(256)
void modresid_kernel(const float* __restrict__ base, const float* __restrict__ xin,
                     float* __restrict__ out,
                     const float* __restrict__ sst, const float* __restrict__ temb,
                     int jg, int FS, long long total)
{
  long long i = (long long)blockIdx.x * 256 + threadIdx.x;
  if (i >= total) return;
  int d = (int)(i % DMODEL);
  int f = (int)((i / DMODEL) / FS);
  float g = sst[jg * DMODEL + d] + temb[(f * 6 + jg) * DMODEL + d];
  out[i] = base[i] + xin[i] * g;
}

__global__ __launch_bounds__(256)
void add_kernel(float* __restrict__ h, const float* __restrict__ x, long long total)
{
  long long i = (long long)blockIdx.x * 256 + threadIdx.x;
  if (i < total) h[i] += x[i];
}

__global__ __launch_bounds__(256)
void cast_kernel(const float* __restrict__ x, bf16* __restrict__ y, long long total)
{
  long long i = (long long)blockIdx.x * 256 + threadIdx.x;
  if (i < total) y[i] = (bf16)x[i];
}

// ---------------- orchestration ----------------
extern "C" void kernel_launch(void* const* d_in, const int* in_sizes, int n_in,
                              void* d_out, int out_size, void* d_ws, size_t ws_size,
                              hipStream_t stream)
{
  const float* hs   = (const float*)d_in[0];
  const float* enc  = (const float*)d_in[1];
  const float* temb = (const float*)d_in[2];
  const float* cosb = (const float*)d_in[3];
  const float* sinb = (const float*)d_in[4];
  const float* sst  = (const float*)d_in[6];
  const float* wq = (const float*)d_in[7];
  const float* wk = (const float*)d_in[8];
  const float* wv = (const float*)d_in[9];
  const float* wo = (const float*)d_in[10];
  const float* bq = (const float*)d_in[11];
  const float* bk = (const float*)d_in[12];
  const float* bv = (const float*)d_in[13];
  const float* bo = (const float*)d_in[14];
  const float* nq_w = (const float*)d_in[15];
  const float* nk_w = (const float*)d_in[16];
  const float* ln2_g = (const float*)d_in[17];
  const float* ln2_b = (const float*)d_in[18];
  const float* cwq = (const float*)d_in[19];
  const float* cwk = (const float*)d_in[20];
  const float* cwv = (const float*)d_in[21];
  const float* cwo = (const float*)d_in[22];
  const float* cbq = (const float*)d_in[23];
  const float* cbk = (const float*)d_in[24];
  const float* cbv = (const float*)d_in[25];
  const float* cbo = (const float*)d_in[26];
  const float* cnq_w = (const float*)d_in[27];
  const float* cnk_w = (const float*)d_in[28];
  const float* w1 = (const float*)d_in[29];
  const float* b1 = (const float*)d_in[30];
  const float* w2 = (const float*)d_in[31];
  const float* b2 = (const float*)d_in[32];

  int L  = in_sizes[0] / DMODEL;
  int LC = in_sizes[1] / DMODEL;
  int F  = in_sizes[2] / (6 * DMODEL);
  int FS = L / F;
  int FF = in_sizes[30];
  long long LD = (long long)L * DMODEL;
  float* outp = (float*)d_out;

  char* p = (char*)d_ws;
  auto alloc = [&](size_t bytes) -> char* {
    char* r = p; p += (bytes + 255) & ~(size_t)255; return r;
  };
  bf16* nh   = (bf16*)alloc((size_t)LD * 2);
  bf16* qb   = (bf16*)alloc((size_t)LD * 2);
  bf16* kb   = (bf16*)alloc((size_t)LD * 2);
  bf16* vb   = (bf16*)alloc((size_t)LD * 2);
  bf16* ab   = (bf16*)alloc((size_t)LD * 2);
  bf16* vtb  = (bf16*)alloc((size_t)LD * 2);
  bf16* vtc  = (bf16*)alloc((size_t)LC * DMODEL * 2);
  bf16* encb = (bf16*)alloc((size_t)LC * DMODEL * 2);
  bf16* ffb  = (bf16*)alloc((size_t)L * FF * 2);
  float* Cf  = (float*)alloc((size_t)LD * 4);
  float* hbuf = (float*)alloc((size_t)LD * 4);
  // transposed bf16 weights
  size_t DD = (size_t)DMODEL * DMODEL;
  bf16* wtq = (bf16*)alloc(DD * 2);
  bf16* wtk = (bf16*)alloc(DD * 2);
  bf16* wtv = (bf16*)alloc(DD * 2);
  bf16* wto = (bf16*)alloc(DD * 2);
  bf16* cwtq = (bf16*)alloc(DD * 2);
  bf16* cwtk = (bf16*)alloc(DD * 2);
  bf16* cwtv = (bf16*)alloc(DD * 2);
  bf16* cwto = (bf16*)alloc(DD * 2);
  bf16* w1t = (bf16*)alloc((size_t)DMODEL * FF * 2);
  bf16* w2t = (bf16*)alloc((size_t)DMODEL * FF * 2);
  (void)ws_size; (void)n_in; (void)out_size;

  // weight transposes (once per launch)
  dim3 gWdd(DMODEL / 32, DMODEL / 32);
  wt_kernel<<<gWdd, 256, 0, stream>>>(wq, wtq, DMODEL, DMODEL);
  wt_kernel<<<gWdd, 256, 0, stream>>>(wk, wtk, DMODEL, DMODEL);
  wt_kernel<<<gWdd, 256, 0, stream>>>(wv, wtv, DMODEL, DMODEL);
  wt_kernel<<<gWdd, 256, 0, stream>>>(wo, wto, DMODEL, DMODEL);
  wt_kernel<<<gWdd, 256, 0, stream>>>(cwq, cwtq, DMODEL, DMODEL);
  wt_kernel<<<gWdd, 256, 0, stream>>>(cwk, cwtk, DMODEL, DMODEL);
  wt_kernel<<<gWdd, 256, 0, stream>>>(cwv, cwtv, DMODEL, DMODEL);
  wt_kernel<<<gWdd, 256, 0, stream>>>(cwo, cwto, DMODEL, DMODEL);
  wt_kernel<<<dim3(DMODEL / 32, FF / 32), 256, 0, stream>>>(w1, w1t, DMODEL, FF);
  wt_kernel<<<dim3(FF / 32, DMODEL / 32), 256, 0, stream>>>(w2, w2t, FF, DMODEL);

  dim3 gD((L + 127) / 128, DMODEL / 128);
  dim3 gC((LC + 127) / 128, DMODEL / 128);
  dim3 gF1((L + 127) / 128, FF / 128);
  int ewg = (int)((LD + 255) / 256);
  int flashg = (NHEADS * (L >> 4) + 3) / 4;

  // 1) AdaLN-modulated LN of hidden
  ln_kernel<<<L, 256, 0, stream>>>(hs, nh, sst, temb, nullptr, nullptr, 0, 1, FS, 0);
  // 2) q/k/v projections
  gemm_bt<<<gD, 256, 0, stream>>>(nh, wtq, bq, Cf, nullptr, L, DMODEL, DMODEL, 0);
  rms_rope_kernel<<<L, 256, 0, stream>>>(Cf, qb, nq_w, cosb, sinb, 1);
  gemm_bt<<<gD, 256, 0, stream>>>(nh, wtk, bk, Cf, nullptr, L, DMODEL, DMODEL, 0);
  rms_rope_kernel<<<L, 256, 0, stream>>>(Cf, kb, nk_w, cosb, sinb, 1);
  gemm_bt<<<gD, 256, 0, stream>>>(nh, wtv, bv, nullptr, vb, L, DMODEL, DMODEL, 0);
  transpose_kernel<<<dim3((L + 63) / 64, DMODEL / 64), 256, 0, stream>>>(vb, vtb, L);
  // 3) self attention (block-causal)
  flash_kernel<<<flashg, 256, 0, stream>>>(qb, kb, vtb, ab, L, L, FS, 1);
  gemm_bt<<<gD, 256, 0, stream>>>(ab, wto, bo, Cf, nullptr, L, DMODEL, DMODEL, 0);
  modresid_kernel<<<ewg, 256, 0, stream>>>(hs, Cf, hbuf, sst, temb, 2, FS, LD);
  // 4) cross attention
  ln_kernel<<<L, 256, 0, stream>>>(hbuf, nh, nullptr, nullptr, ln2_g, ln2_b, 0, 0, FS, 1);
  gemm_bt<<<gD, 256, 0, stream>>>(nh, cwtq, cbq, Cf, nullptr, L, DMODEL, DMODEL, 0);
  rms_rope_kernel<<<L, 256, 0, stream>>>(Cf, qb, cnq_w, nullptr, nullptr, 0);
  cast_kernel<<<(int)(((long long)LC * DMODEL + 255) / 256), 256, 0, stream>>>(enc, encb, (long long)LC * DMODEL);
  gemm_bt<<<gC, 256, 0, stream>>>(encb, cwtk, cbk, Cf, nullptr, LC, DMODEL, DMODEL, 0);
  rms_rope_kernel<<<LC, 256, 0, stream>>>(Cf, kb, cnk_w, nullptr, nullptr, 0);
  gemm_bt<<<gC, 256, 0, stream>>>(encb, cwtv, cbv, nullptr, vb, LC, DMODEL, DMODEL, 0);
  transpose_kernel<<<dim3((LC + 63) / 64, DMODEL / 64), 256, 0, stream>>>(vb, vtc, LC);
  flash_kernel<<<flashg, 256, 0, stream>>>(qb, kb, vtc, ab, L, LC, FS, 0);
  gemm_bt<<<gD, 256, 0, stream>>>(ab, cwto, cbo, Cf, nullptr, L, DMODEL, DMODEL, 0);
  add_kernel<<<ewg, 256, 0, stream>>>(hbuf, Cf, LD);
  // 5) FFN with AdaLN modulate + gated residual
  ln_kernel<<<L, 256, 0, stream>>>(hbuf, nh, sst, temb, nullptr, nullptr, 3, 4, FS, 0);
  gemm_bt<<<gF1, 256, 0, stream>>>(nh, w1t, b1, nullptr, ffb, L, FF, DMODEL, 1);
  gemm_bt<<<gD, 256, 0, stream>>>(ffb, w2t, b2, Cf, nullptr, L, DMODEL, FF, 0);
  modresid_kernel<<<ewg, 256, 0, stream>>>(hbuf, Cf, outp, sst, temb, 5, FS, LD);
}

// Round 3
// 1402.405 us; speedup vs baseline: 1.6268x; 1.1678x over previous
//
#include <hip/hip_runtime.h>
#include <hip/hip_bf16.h>
#include <math.h>

typedef __bf16 bf16;
typedef __bf16 bf16x8 __attribute__((ext_vector_type(8)));
typedef float  f32x4  __attribute__((ext_vector_type(4)));
typedef unsigned int u32;

#define DMODEL 1536
#define NHEADS 12
#define HD 128
#define HDH 64

__device__ __forceinline__ void async16(const void* g, void* l) {
  __builtin_amdgcn_global_load_lds((const __attribute__((address_space(1))) u32*)g,
                                   (__attribute__((address_space(3))) u32*)l, 16, 0, 0);
}

// ---------------- block reduction (block = 256) ----------------
__device__ inline void block_reduce2(float& a, float& b) {
  __shared__ float sa[4], sb[4];
  #pragma unroll
  for (int off = 32; off; off >>= 1) {
    a += __shfl_xor(a, off);
    b += __shfl_xor(b, off);
  }
  int w = threadIdx.x >> 6;
  if ((threadIdx.x & 63) == 0) { sa[w] = a; sb[w] = b; }
  __syncthreads();
  a = sa[0] + sa[1] + sa[2] + sa[3];
  b = sb[0] + sb[1] + sb[2] + sb[3];
  __syncthreads();
}

// ---------------- LayerNorm (+AdaLN modulate or affine) ----------------
__global__ __launch_bounds__(256)
void ln_kernel(const float* __restrict__ X, bf16* __restrict__ Y,
               const float* __restrict__ sst, const float* __restrict__ temb,
               const float* __restrict__ g, const float* __restrict__ bvec,
               int jshift, int jscale, int FS, int mode)
{
  int row = blockIdx.x;
  const float* x = X + (size_t)row * DMODEL;
  float v[6];
  float s1 = 0.f, s2 = 0.f;
  #pragma unroll
  for (int i = 0; i < 6; i++) {
    float t = x[threadIdx.x + i * 256];
    v[i] = t; s1 += t; s2 += t * t;
  }
  block_reduce2(s1, s2);
  float mean = s1 * (1.f / DMODEL);
  float var  = s2 * (1.f / DMODEL) - mean * mean;
  float rs = rsqrtf(var + 1e-6f);
  int f = row / FS;
  bf16* y = Y + (size_t)row * DMODEL;
  #pragma unroll
  for (int i = 0; i < 6; i++) {
    int d = threadIdx.x + i * 256;
    float t = (v[i] - mean) * rs;
    float o;
    if (mode == 0) {
      float sc = sst[jscale * DMODEL + d] + temb[(f * 6 + jscale) * DMODEL + d];
      float sh = sst[jshift * DMODEL + d] + temb[(f * 6 + jshift) * DMODEL + d];
      o = t * (1.f + sc) + sh;
    } else {
      o = t * g[d] + bvec[d];
    }
    y[d] = (bf16)o;
  }
}

// ---------------- RMSNorm (+ optional interleaved RoPE), output scaled ----------------
__global__ __launch_bounds__(256)
void rms_rope_kernel(const float* __restrict__ X, bf16* __restrict__ Y,
                     const float* __restrict__ w,
                     const float* __restrict__ cosb, const float* __restrict__ sinb,
                     int dorope, float oscale)
{
  int row = blockIdx.x;
  const float* x = X + (size_t)row * DMODEL;
  float v[6];
  float s2 = 0.f, dummy = 0.f;
  #pragma unroll
  for (int i = 0; i < 6; i++) {
    float t = x[threadIdx.x + i * 256];
    v[i] = t; s2 += t * t;
  }
  block_reduce2(s2, dummy);
  float rs = rsqrtf(s2 * (1.f / DMODEL) + 1e-6f) * oscale;
  bf16* y = Y + (size_t)row * DMODEL;
  if (dorope) {
    #pragma unroll
    for (int i = 0; i < 3; i++) {
      int p = threadIdx.x + i * 256;
      int d0 = 2 * p, d1 = 2 * p + 1;
      float y0 = x[d0] * rs * w[d0];
      float y1 = x[d1] * rs * w[d1];
      int ih = p & 63;
      float c = cosb[(size_t)row * HDH + ih];
      float s = sinb[(size_t)row * HDH + ih];
      y[d0] = (bf16)(y0 * c - y1 * s);
      y[d1] = (bf16)(y0 * s + y1 * c);
    }
  } else {
    #pragma unroll
    for (int i = 0; i < 6; i++) {
      int d = threadIdx.x + i * 256;
      y[d] = (bf16)(v[i] * rs * w[d]);
    }
  }
}

// ---------------- weight transpose+cast: W (K,N) fp32 -> Wt (N,K) bf16 ----------------
__global__ __launch_bounds__(256)
void wt_kernel(const float* __restrict__ W, bf16* __restrict__ Wt, int K, int N)
{
  __shared__ float T[32][33];
  int k0 = blockIdx.x * 32, n0 = blockIdx.y * 32;
  int tx = threadIdx.x & 31, ty = threadIdx.x >> 5;
  #pragma unroll
  for (int i = 0; i < 4; i++)
    T[ty + 8 * i][tx] = W[(size_t)(k0 + ty + 8 * i) * N + n0 + tx];
  __syncthreads();
  #pragma unroll
  for (int i = 0; i < 4; i++)
    Wt[(size_t)(n0 + ty + 8 * i) * K + k0 + tx] = (bf16)T[tx][ty + 8 * i];
}

// ---------------- GEMM m97-style ----------------
__global__ __launch_bounds__(256)
void gemm_bt(const bf16* __restrict__ A, const bf16* __restrict__ Bt,
             const float* __restrict__ bias, float* __restrict__ Cf,
             bf16* __restrict__ Cb, int M, int N, int K, int act)
{
  __shared__ bf16 As[128 * 32];
  __shared__ bf16 Bs[128 * 32];
  int tid = threadIdx.x, lane = tid & 63, w = tid >> 6;
  int wm = w >> 1, wn = w & 1;
  int l16 = lane & 15, quad = lane >> 4;
  int bm = blockIdx.x * 128, bn = blockIdx.y * 128;

  int rl = lane >> 2;
  int kk = (lane & 3) * 8;
  int r0 = (2 * w) * 16 + rl, r1 = (2 * w + 1) * 16 + rl;
  int am0 = bm + r0; if (am0 > M - 1) am0 = M - 1;
  int am1 = bm + r1; if (am1 > M - 1) am1 = M - 1;
  const bf16* a0 = A + (size_t)am0 * K + kk;
  const bf16* a1 = A + (size_t)am1 * K + kk;
  const bf16* b0 = Bt + (size_t)(bn + r0) * K + kk;
  const bf16* b1 = Bt + (size_t)(bn + r1) * K + kk;
  bf16* lA0 = As + (2 * w) * 512; bf16* lA1 = As + (2 * w + 1) * 512;
  bf16* lB0 = Bs + (2 * w) * 512; bf16* lB1 = Bs + (2 * w + 1) * 512;

  f32x4 acc[4][4] = {};
  for (int k0 = 0; k0 < K; k0 += 32) {
    async16(a0 + k0, lA0);
    async16(a1 + k0, lA1);
    async16(b0 + k0, lB0);
    async16(b1 + k0, lB1);
    __syncthreads();
    bf16x8 af[4], bfv[4];
    #pragma unroll
    for (int mi = 0; mi < 4; mi++)
      af[mi] = *(const bf16x8*)&As[(wm * 64 + mi * 16 + l16) * 32 + quad * 8];
    #pragma unroll
    for (int ni = 0; ni < 4; ni++)
      bfv[ni] = *(const bf16x8*)&Bs[(wn * 64 + ni * 16 + l16) * 32 + quad * 8];
    #pragma unroll
    for (int mi = 0; mi < 4; mi++)
      #pragma unroll
      for (int ni = 0; ni < 4; ni++)
        acc[mi][ni] = __builtin_amdgcn_mfma_f32_16x16x32_bf16(af[mi], bfv[ni], acc[mi][ni], 0, 0, 0);
    __syncthreads();
  }
  #pragma unroll
  for (int mi = 0; mi < 4; mi++) {
    #pragma unroll
    for (int r = 0; r < 4; r++) {
      int m = bm + wm * 64 + mi * 16 + quad * 4 + r;
      if (m < M) {
        #pragma unroll
        for (int ni = 0; ni < 4; ni++) {
          int n = bn + wn * 64 + ni * 16 + l16;
          float val = acc[mi][ni][r] + bias[n];
          if (act == 1) {
            float u = val + 0.044715f * val * val * val;
            float z = 1.5957691216057308f * u;
            val = val / (1.f + __expf(-z));
          }
          if (Cf) Cf[(size_t)m * N + n] = val;
          else    Cb[(size_t)m * N + n] = (bf16)val;
        }
      }
    }
  }
}

// ---------------- transpose V (Lx1536 -> 1536xL) ----------------
__global__ __launch_bounds__(256)
void transpose_kernel(const bf16* __restrict__ V, bf16* __restrict__ Vt, int L)
{
  __shared__ bf16 T[64][65];
  int l0 = blockIdx.x * 64, n0 = blockIdx.y * 64;
  int tid = threadIdx.x;
  int r = tid >> 2;
  int c8 = (tid & 3) * 16;
  if (l0 + r < L) {
    #pragma unroll
    for (int i = 0; i < 16; i++)
      T[r][c8 + i] = V[(size_t)(l0 + r) * DMODEL + n0 + c8 + i];
  } else {
    #pragma unroll
    for (int i = 0; i < 16; i++) T[r][c8 + i] = (bf16)0.f;
  }
  __syncthreads();
  #pragma unroll
  for (int i = 0; i < 16; i++) {
    int l = l0 + c8 + i;
    if (l < L) Vt[(size_t)(n0 + r) * L + l] = T[c8 + i][r];
  }
}

// ---------------- flash attention v2: block-cooperative, LDS-staged ----------------
// Block = 4 waves = one head x 64 queries. K-step = 64 keys.
// Kt: 64 keys x 128 d, XOR-swizzled 16B units. Vtile: 128 d x 64 keys, swizzled.
// Q pre-scaled by 1/sqrt(hd).
__global__ __launch_bounds__(256)
void flash2_kernel(const bf16* __restrict__ Q, const bf16* __restrict__ Kg,
                   const bf16* __restrict__ Vt, bf16* __restrict__ O,
                   int Lq, int Lk, int FS, int causal, int nqb)
{
  __shared__ bf16 Kt[64 * 128];
  __shared__ bf16 Vtile[128 * 64];
  __shared__ bf16 Pl[4][16][72];
  int tid = threadIdx.x, lane = tid & 63, w = tid >> 6;
  int l16 = lane & 15, quad = lane >> 4;
  int bid = blockIdx.x;
  int h = bid % NHEADS;
  int qb = nqb - 1 - (bid / NHEADS);   // heavy (high-q) blocks dispatched first
  int q0b = qb * 64;
  int q0w = q0b + w * 16;

  // Q fragments (rows clamped; duplicates masked at write)
  int qrow = q0w + l16; if (qrow > Lq - 1) qrow = Lq - 1;
  const bf16* qbase = Q + (size_t)qrow * DMODEL + h * HD + quad * 8;
  bf16x8 qf[4];
  #pragma unroll
  for (int dc = 0; dc < 4; dc++) qf[dc] = *(const bf16x8*)(qbase + dc * 32);

  int kvrow[4];
  int kvmin_w = Lk, kv_end = Lk;
  if (causal) {
    #pragma unroll
    for (int r = 0; r < 4; r++) {
      int qr = q0w + quad * 4 + r; if (qr > Lq - 1) qr = Lq - 1;
      kvrow[r] = (qr / FS + 1) * FS;
    }
    int q0c = q0w; if (q0c > Lq - 1) q0c = Lq - 1;
    kvmin_w = (q0c / FS + 1) * FS;
    int qlast = q0b + 63; if (qlast > Lq - 1) qlast = Lq - 1;
    kv_end = (qlast / FS + 1) * FS;
    if (kv_end > Lk) kv_end = Lk;
  }

  f32x4 acc_o[8] = {};
  float m_i[4], l_i[4];
  #pragma unroll
  for (int r = 0; r < 4; r++) { m_i[r] = -1e30f; l_i[r] = 0.f; }

  for (int kb = 0; kb < kv_end; kb += 64) {
    // ---- stage K tile: 1024 x 16B units, swizzled: unit u -> row u/16, cu = (u%16)^(row%16)
    #pragma unroll
    for (int j = 0; j < 4; j++) {
      int u = w * 256 + j * 64 + lane;
      int row = u >> 4;
      int c = (u & 15) ^ (row & 15);
      int krow = kb + row; if (krow > Lk - 1) krow = Lk - 1;
      async16(Kg + (size_t)krow * DMODEL + h * HD + c * 8,
              Kt + (size_t)(w * 256 + j * 64) * 8);
    }
    // ---- stage V^T tile: rows = d (128), 8 units/row, cu = (u%8)^(row%8)
    #pragma unroll
    for (int j = 0; j < 4; j++) {
      int u = w * 256 + j * 64 + lane;
      int row = u >> 3;
      int c = (u & 7) ^ (row & 7);
      async16(Vt + (size_t)(h * HD + row) * Lk + kb + c * 8,
              Vtile + (size_t)(w * 256 + j * 64) * 8);
    }
    __syncthreads();

    // ---- QK^T: 16 queries x 64 keys per wave
    f32x4 s[4] = {};
    #pragma unroll
    for (int nk = 0; nk < 4; nk++) {
      #pragma unroll
      for (int dc = 0; dc < 4; dc++) {
        bf16x8 kf = *(const bf16x8*)&Kt[(((nk * 16 + l16) << 4) + ((4 * dc + quad) ^ l16)) * 8];
        s[nk] = __builtin_amdgcn_mfma_f32_16x16x32_bf16(qf[dc], kf, s[nk], 0, 0, 0);
      }
    }

    // ---- online softmax
    bool need_mask = causal && (kb + 64 > kvmin_w);
    float p[4][4];
    #pragma unroll
    for (int r = 0; r < 4; r++) {
      #pragma unroll
      for (int nk = 0; nk < 4; nk++) {
        float sv = s[nk][r];
        if (need_mask && (kb + nk * 16 + l16 >= kvrow[r])) sv = -1e30f;
        p[nk][r] = sv;
      }
      float bm = fmaxf(fmaxf(p[0][r], p[1][r]), fmaxf(p[2][r], p[3][r]));
      #pragma unroll
      for (int off = 8; off; off >>= 1) bm = fmaxf(bm, __shfl_xor(bm, off));
      float mn = fmaxf(m_i[r], bm);
      float alpha = __expf(m_i[r] - mn);
      m_i[r] = mn;
      float ps = 0.f;
      #pragma unroll
      for (int nk = 0; nk < 4; nk++) {
        float e = __expf(p[nk][r] - mn);
        p[nk][r] = e; ps += e;
      }
      #pragma unroll
      for (int off = 8; off; off >>= 1) ps += __shfl_xor(ps, off);
      l_i[r] = l_i[r] * alpha + ps;
      #pragma unroll
      for (int t = 0; t < 8; t++) acc_o[t][r] *= alpha;
    }

    // ---- P -> LDS (C-layout) -> A-frag
    #pragma unroll
    for (int nk = 0; nk < 4; nk++)
      #pragma unroll
      for (int r = 0; r < 4; r++)
        Pl[w][quad * 4 + r][nk * 16 + l16] = (bf16)p[nk][r];
    __threadfence_block();
    bf16x8 pf0 = *(const bf16x8*)&Pl[w][l16][quad * 8];
    bf16x8 pf1 = *(const bf16x8*)&Pl[w][l16][32 + quad * 8];

    // ---- P @ V
    #pragma unroll
    for (int t = 0; t < 8; t++) {
      bf16x8 vf0 = *(const bf16x8*)&Vtile[(((t * 16 + l16) << 3) + ((quad) ^ (l16 & 7))) * 8];
      bf16x8 vf1 = *(const bf16x8*)&Vtile[(((t * 16 + l16) << 3) + ((4 + quad) ^ (l16 & 7))) * 8];
      acc_o[t] = __builtin_amdgcn_mfma_f32_16x16x32_bf16(pf0, vf0, acc_o[t], 0, 0, 0);
      acc_o[t] = __builtin_amdgcn_mfma_f32_16x16x32_bf16(pf1, vf1, acc_o[t], 0, 0, 0);
    }
    __syncthreads();
  }

  #pragma unroll
  for (int r = 0; r < 4; r++) {
    int m = q0w + quad * 4 + r;
    if (m < Lq) {
      float inv = 1.f / l_i[r];
      bf16* obase = O + (size_t)m * DMODEL + h * HD;
      #pragma unroll
      for (int t = 0; t < 8; t++)
        obase[t * 16 + l16] = (bf16)(acc_o[t][r] * inv);
    }
  }
}

// ---------------- elementwise ----------------
__global__ __launch_bounds__(256)
void modresid_kernel(const float* __restrict__ base, const float* __restrict__ xin,
                     float* __restrict__ out,
                     const float* __restrict__ sst, const float* __restrict__ temb,
                     int jg, int FS, long long total)
{
  long long i = (long long)blockIdx.x * 256 + threadIdx.x;
  if (i >= total) return;
  int d = (int)(i % DMODEL);
  int f = (int)((i / DMODEL) / FS);
  float g = sst[jg * DMODEL + d] + temb[(f * 6 + jg) * DMODEL + d];
  out[i] = base[i] + xin[i] * g;
}

__global__ __launch_bounds__(256)
void add_kernel(float* __restrict__ h, const float* __restrict__ x, long long total)
{
  long long i = (long long)blockIdx.x * 256 + threadIdx.x;
  if (i < total) h[i] += x[i];
}

__global__ __launch_bounds__(256)
void cast_kernel(const float* __restrict__ x, bf16* __restrict__ y, long long total)
{
  long long i = (long long)blockIdx.x * 256 + threadIdx.x;
  if (i < total) y[i] = (bf16)x[i];
}

// ---------------- orchestration ----------------
extern "C" void kernel_launch(void* const* d_in, const int* in_sizes, int n_in,
                              void* d_out, int out_size, void* d_ws, size_t ws_size,
                              hipStream_t stream)
{
  const float* hs   = (const float*)d_in[0];
  const float* enc  = (const float*)d_in[1];
  const float* temb = (const float*)d_in[2];
  const float* cosb = (const float*)d_in[3];
  const float* sinb = (const float*)d_in[4];
  const float* sst  = (const float*)d_in[6];
  const float* wq = (const float*)d_in[7];
  const float* wk = (const float*)d_in[8];
  const float* wv = (const float*)d_in[9];
  const float* wo = (const float*)d_in[10];
  const float* bq = (const float*)d_in[11];
  const float* bk = (const float*)d_in[12];
  const float* bv = (const float*)d_in[13];
  const float* bo = (const float*)d_in[14];
  const float* nq_w = (const float*)d_in[15];
  const float* nk_w = (const float*)d_in[16];
  const float* ln2_g = (const float*)d_in[17];
  const float* ln2_b = (const float*)d_in[18];
  const float* cwq = (const float*)d_in[19];
  const float* cwk = (const float*)d_in[20];
  const float* cwv = (const float*)d_in[21];
  const float* cwo = (const float*)d_in[22];
  const float* cbq = (const float*)d_in[23];
  const float* cbk = (const float*)d_in[24];
  const float* cbv = (const float*)d_in[25];
  const float* cbo = (const float*)d_in[26];
  const float* cnq_w = (const float*)d_in[27];
  const float* cnk_w = (const float*)d_in[28];
  const float* w1 = (const float*)d_in[29];
  const float* b1 = (const float*)d_in[30];
  const float* w2 = (const float*)d_in[31];
  const float* b2 = (const float*)d_in[32];

  int L  = in_sizes[0] / DMODEL;
  int LC = in_sizes[1] / DMODEL;
  int F  = in_sizes[2] / (6 * DMODEL);
  int FS = L / F;
  int FF = in_sizes[30];
  long long LD = (long long)L * DMODEL;
  float* outp = (float*)d_out;

  char* p = (char*)d_ws;
  auto alloc = [&](size_t bytes) -> char* {
    char* r = p; p += (bytes + 255) & ~(size_t)255; return r;
  };
  bf16* nh   = (bf16*)alloc((size_t)LD * 2);
  bf16* qb   = (bf16*)alloc((size_t)LD * 2);
  bf16* kb   = (bf16*)alloc((size_t)LD * 2);
  bf16* vb   = (bf16*)alloc((size_t)LD * 2);
  bf16* ab   = (bf16*)alloc((size_t)LD * 2);
  bf16* vtb  = (bf16*)alloc((size_t)LD * 2);
  bf16* vtc  = (bf16*)alloc((size_t)LC * DMODEL * 2);
  bf16* encb = (bf16*)alloc((size_t)LC * DMODEL * 2);
  bf16* ffb  = (bf16*)alloc((size_t)L * FF * 2);
  float* Cf  = (float*)alloc((size_t)LD * 4);
  float* hbuf = (float*)alloc((size_t)LD * 4);
  size_t DD = (size_t)DMODEL * DMODEL;
  bf16* wtq = (bf16*)alloc(DD * 2);
  bf16* wtk = (bf16*)alloc(DD * 2);
  bf16* wtv = (bf16*)alloc(DD * 2);
  bf16* wto = (bf16*)alloc(DD * 2);
  bf16* cwtq = (bf16*)alloc(DD * 2);
  bf16* cwtk = (bf16*)alloc(DD * 2);
  bf16* cwtv = (bf16*)alloc(DD * 2);
  bf16* cwto = (bf16*)alloc(DD * 2);
  bf16* w1t = (bf16*)alloc((size_t)DMODEL * FF * 2);
  bf16* w2t = (bf16*)alloc((size_t)DMODEL * FF * 2);
  (void)ws_size; (void)n_in; (void)out_size;

  dim3 gWdd(DMODEL / 32, DMODEL / 32);
  wt_kernel<<<gWdd, 256, 0, stream>>>(wq, wtq, DMODEL, DMODEL);
  wt_kernel<<<gWdd, 256, 0, stream>>>(wk, wtk, DMODEL, DMODEL);
  wt_kernel<<<gWdd, 256, 0, stream>>>(wv, wtv, DMODEL, DMODEL);
  wt_kernel<<<gWdd, 256, 0, stream>>>(wo, wto, DMODEL, DMODEL);
  wt_kernel<<<gWdd, 256, 0, stream>>>(cwq, cwtq, DMODEL, DMODEL);
  wt_kernel<<<gWdd, 256, 0, stream>>>(cwk, cwtk, DMODEL, DMODEL);
  wt_kernel<<<gWdd, 256, 0, stream>>>(cwv, cwtv, DMODEL, DMODEL);
  wt_kernel<<<gWdd, 256, 0, stream>>>(cwo, cwto, DMODEL, DMODEL);
  wt_kernel<<<dim3(DMODEL / 32, FF / 32), 256, 0, stream>>>(w1, w1t, DMODEL, FF);
  wt_kernel<<<dim3(FF / 32, DMODEL / 32), 256, 0, stream>>>(w2, w2t, FF, DMODEL);

  dim3 gD((L + 127) / 128, DMODEL / 128);
  dim3 gC((LC + 127) / 128, DMODEL / 128);
  dim3 gF1((L + 127) / 128, FF / 128);
  int ewg = (int)((LD + 255) / 256);
  int nqb = (L + 63) / 64;
  const float qs = 0.08838834764831845f;  // 1/sqrt(128)

  // 1) AdaLN-modulated LN of hidden
  ln_kernel<<<L, 256, 0, stream>>>(hs, nh, sst, temb, nullptr, nullptr, 0, 1, FS, 0);
  // 2) q/k/v projections
  gemm_bt<<<gD, 256, 0, stream>>>(nh, wtq, bq, Cf, nullptr, L, DMODEL, DMODEL, 0);
  rms_rope_kernel<<<L, 256, 0, stream>>>(Cf, qb, nq_w, cosb, sinb, 1, qs);
  gemm_bt<<<gD, 256, 0, stream>>>(nh, wtk, bk, Cf, nullptr, L, DMODEL, DMODEL, 0);
  rms_rope_kernel<<<L, 256, 0, stream>>>(Cf, kb, nk_w, cosb, sinb, 1, 1.0f);
  gemm_bt<<<gD, 256, 0, stream>>>(nh, wtv, bv, nullptr, vb, L, DMODEL, DMODEL, 0);
  transpose_kernel<<<dim3((L + 63) / 64, DMODEL / 64), 256, 0, stream>>>(vb, vtb, L);
  // 3) self attention (block-causal)
  flash2_kernel<<<NHEADS * nqb, 256, 0, stream>>>(qb, kb, vtb, ab, L, L, FS, 1, nqb);
  gemm_bt<<<gD, 256, 0, stream>>>(ab, wto, bo, Cf, nullptr, L, DMODEL, DMODEL, 0);
  modresid_kernel<<<ewg, 256, 0, stream>>>(hs, Cf, hbuf, sst, temb, 2, FS, LD);
  // 4) cross attention
  ln_kernel<<<L, 256, 0, stream>>>(hbuf, nh, nullptr, nullptr, ln2_g, ln2_b, 0, 0, FS, 1);
  gemm_bt<<<gD, 256, 0, stream>>>(nh, cwtq, cbq, Cf, nullptr, L, DMODEL, DMODEL, 0);
  rms_rope_kernel<<<L, 256, 0, stream>>>(Cf, qb, cnq_w, nullptr, nullptr, 0, qs);
  cast_kernel<<<(int)(((long long)LC * DMODEL + 255) / 256), 256, 0, stream>>>(enc, encb, (long long)LC * DMODEL);
  gemm_bt<<<gC, 256, 0, stream>>>(encb, cwtk, cbk, Cf, nullptr, LC, DMODEL, DMODEL, 0);
  rms_rope_kernel<<<LC, 256, 0, stream>>>(Cf, kb, cnk_w, nullptr, nullptr, 0, 1.0f);
  gemm_bt<<<gC, 256, 0, stream>>>(encb, cwtv, cbv, nullptr, vb, LC, DMODEL, DMODEL, 0);
  transpose_kernel<<<dim3((LC + 63) / 64, DMODEL / 64), 256, 0, stream>>>(vb, vtc, LC);
  flash2_kernel<<<NHEADS * nqb, 256, 0, stream>>>(qb, kb, vtc, ab, L, LC, FS, 0, nqb);
  gemm_bt<<<gD, 256, 0, stream>>>(ab, cwto, cbo, Cf, nullptr, L, DMODEL, DMODEL, 0);
  add_kernel<<<ewg, 256, 0, stream>>>(hbuf, Cf, LD);
  // 5) FFN
  ln_kernel<<<L, 256, 0, stream>>>(hbuf, nh, sst, temb, nullptr, nullptr, 3, 4, FS, 0);
  gemm_bt<<<gF1, 256, 0, stream>>>(nh, w1t, b1, nullptr, ffb, L, FF, DMODEL, 1);
  gemm_bt<<<gD, 256, 0, stream>>>(ffb, w2t, b2, Cf, nullptr, L, DMODEL, FF, 0);
  modresid_kernel<<<ewg, 256, 0, stream>>>(hbuf, Cf, outp, sst, temb, 5, FS, LD);
}

// Round 5
// 1228.695 us; speedup vs baseline: 1.8567x; 1.1414x over previous
//
#include <hip/hip_runtime.h>
#include <hip/hip_bf16.h>
#include <math.h>

typedef __bf16 bf16;
typedef __bf16 bf16x8 __attribute__((ext_vector_type(8)));
typedef float  f32x4  __attribute__((ext_vector_type(4)));
typedef unsigned int u32;

#define DMODEL 1536
#define NHEADS 12
#define HD 128
#define HDH 64

__device__ __forceinline__ void async16(const void* g, void* l) {
  __builtin_amdgcn_global_load_lds((const __attribute__((address_space(1))) u32*)g,
                                   (__attribute__((address_space(3))) u32*)l, 16, 0, 0);
}

// ---------------- block reduction (block = 256) ----------------
__device__ inline void block_reduce2(float& a, float& b) {
  __shared__ float sa[4], sb[4];
  #pragma unroll
  for (int off = 32; off; off >>= 1) {
    a += __shfl_xor(a, off);
    b += __shfl_xor(b, off);
  }
  int w = threadIdx.x >> 6;
  if ((threadIdx.x & 63) == 0) { sa[w] = a; sb[w] = b; }
  __syncthreads();
  a = sa[0] + sa[1] + sa[2] + sa[3];
  b = sb[0] + sb[1] + sb[2] + sb[3];
  __syncthreads();
}

// ---------------- LayerNorm (+AdaLN modulate or affine) ----------------
__global__ __launch_bounds__(256)
void ln_kernel(const float* __restrict__ X, bf16* __restrict__ Y,
               const float* __restrict__ sst, const float* __restrict__ temb,
               const float* __restrict__ g, const float* __restrict__ bvec,
               int jshift, int jscale, int FS, int mode)
{
  int row = blockIdx.x;
  const float* x = X + (size_t)row * DMODEL;
  float v[6];
  float s1 = 0.f, s2 = 0.f;
  #pragma unroll
  for (int i = 0; i < 6; i++) {
    float t = x[threadIdx.x + i * 256];
    v[i] = t; s1 += t; s2 += t * t;
  }
  block_reduce2(s1, s2);
  float mean = s1 * (1.f / DMODEL);
  float var  = s2 * (1.f / DMODEL) - mean * mean;
  float rs = rsqrtf(var + 1e-6f);
  int f = row / FS;
  bf16* y = Y + (size_t)row * DMODEL;
  #pragma unroll
  for (int i = 0; i < 6; i++) {
    int d = threadIdx.x + i * 256;
    float t = (v[i] - mean) * rs;
    float o;
    if (mode == 0) {
      float sc = sst[jscale * DMODEL + d] + temb[(f * 6 + jscale) * DMODEL + d];
      float sh = sst[jshift * DMODEL + d] + temb[(f * 6 + jshift) * DMODEL + d];
      o = t * (1.f + sc) + sh;
    } else {
      o = t * g[d] + bvec[d];
    }
    y[d] = (bf16)o;
  }
}

// ---------------- RMSNorm (+ optional RoPE), dual-mode input ----------------
// If Xb != null: x[d] = (float)Xb[row*RS + CO + d]           (bias pre-applied)
// Else:          x[d] = bias[d] + sum_{s<S} P[s*MN + row*RS + CO + d]
__global__ __launch_bounds__(256)
void rms_rope_kernel(const float* __restrict__ P, int S, long long MN,
                     const bf16* __restrict__ Xb, int RS, int CO,
                     const float* __restrict__ bias, bf16* __restrict__ Y,
                     const float* __restrict__ w,
                     const float* __restrict__ cosb, const float* __restrict__ sinb,
                     int dorope, float oscale)
{
  __shared__ float rowbuf[DMODEL];
  int row = blockIdx.x;
  float v[6];
  float s2 = 0.f, dummy = 0.f;
  if (Xb) {
    const bf16* x = Xb + (size_t)row * RS + CO;
    #pragma unroll
    for (int i = 0; i < 6; i++) {
      int d = threadIdx.x + i * 256;
      float t = (float)x[d];
      v[i] = t; rowbuf[d] = t; s2 += t * t;
    }
  } else {
    const float* x = P + (size_t)row * RS + CO;
    #pragma unroll
    for (int i = 0; i < 6; i++) {
      int d = threadIdx.x + i * 256;
      float t = bias[d];
      for (int s = 0; s < S; s++) t += x[(size_t)s * MN + d];
      v[i] = t; rowbuf[d] = t; s2 += t * t;
    }
  }
  __syncthreads();
  block_reduce2(s2, dummy);
  float rs = rsqrtf(s2 * (1.f / DMODEL) + 1e-6f) * oscale;
  bf16* y = Y + (size_t)row * DMODEL;
  if (dorope) {
    #pragma unroll
    for (int i = 0; i < 3; i++) {
      int p = threadIdx.x + i * 256;
      int d0 = 2 * p, d1 = 2 * p + 1;
      float y0 = rowbuf[d0] * rs * w[d0];
      float y1 = rowbuf[d1] * rs * w[d1];
      int ih = p & 63;
      float c = cosb[(size_t)row * HDH + ih];
      float s = sinb[(size_t)row * HDH + ih];
      y[d0] = (bf16)(y0 * c - y1 * s);
      y[d1] = (bf16)(y0 * s + y1 * c);
    }
  } else {
    #pragma unroll
    for (int i = 0; i < 6; i++) {
      int d = threadIdx.x + i * 256;
      y[d] = (bf16)(v[i] * rs * w[d]);
    }
  }
}

// ---------------- weight transpose+cast: W (K,N) fp32 -> Wt (N,K) bf16 ----------------
__global__ __launch_bounds__(256)
void wt_kernel(const float* __restrict__ W, bf16* __restrict__ Wt, int K, int N)
{
  __shared__ float T[32][33];
  int k0 = blockIdx.x * 32, n0 = blockIdx.y * 32;
  int tx = threadIdx.x & 31, ty = threadIdx.x >> 5;
  #pragma unroll
  for (int i = 0; i < 4; i++)
    T[ty + 8 * i][tx] = W[(size_t)(k0 + ty + 8 * i) * N + n0 + tx];
  __syncthreads();
  #pragma unroll
  for (int i = 0; i < 4; i++)
    Wt[(size_t)(n0 + ty + 8 * i) * K + k0 + tx] = (bf16)T[tx][ty + 8 * i];
}

// ---------------- bias concat ----------------
__global__ __launch_bounds__(256)
void catbias_kernel(float* __restrict__ bqkv, const float* __restrict__ bq,
                    const float* __restrict__ bk, const float* __restrict__ bv,
                    float* __restrict__ cbkv, const float* __restrict__ cbk,
                    const float* __restrict__ cbv)
{
  int i = blockIdx.x * 256 + threadIdx.x;
  if (i < DMODEL) {
    bqkv[i] = bq[i]; bqkv[DMODEL + i] = bk[i]; bqkv[2 * DMODEL + i] = bv[i];
    cbkv[i] = cbk[i]; cbkv[DMODEL + i] = cbv[i];
  }
}

// ---------------- GEMM m97-style, swizzled grid + optional split-K ----------------
__global__ __launch_bounds__(256)
void gemm_bt(const bf16* __restrict__ A, const bf16* __restrict__ Bt,
             const float* __restrict__ bias, float* __restrict__ Cf,
             bf16* __restrict__ Cb, int M, int N, int K, int act,
             int Ks, long long MN)
{
  __shared__ bf16 As[128 * 32];
  __shared__ bf16 Bs[128 * 32];
  int tid = threadIdx.x, lane = tid & 63, w = tid >> 6;
  int wm = w >> 1, wn = w & 1;
  int l16 = lane & 15, quad = lane >> 4;

  int gx = (M + 127) >> 7, gy = N >> 7;
  int per_panel = gx << 3;
  int bid = blockIdx.x;
  int panel = bid / per_panel;
  int rem = bid - panel * per_panel;
  int pc0 = panel << 3;
  int ncols = gy - pc0; if (ncols > 8) ncols = 8;
  int by = pc0 + rem % ncols;
  int bx = rem / ncols;
  int bm = bx * 128, bn = by * 128;

  int kb0 = blockIdx.y * Ks;

  int rl = lane >> 2;
  int kk = (lane & 3) * 8;
  int r0 = (2 * w) * 16 + rl, r1 = (2 * w + 1) * 16 + rl;
  int am0 = bm + r0; if (am0 > M - 1) am0 = M - 1;
  int am1 = bm + r1; if (am1 > M - 1) am1 = M - 1;
  const bf16* a0 = A + (size_t)am0 * K + kk;
  const bf16* a1 = A + (size_t)am1 * K + kk;
  const bf16* b0 = Bt + (size_t)(bn + r0) * K + kk;
  const bf16* b1 = Bt + (size_t)(bn + r1) * K + kk;
  bf16* lA0 = As + (2 * w) * 512; bf16* lA1 = As + (2 * w + 1) * 512;
  bf16* lB0 = Bs + (2 * w) * 512; bf16* lB1 = Bs + (2 * w + 1) * 512;

  f32x4 acc[4][4] = {};
  int kend = kb0 + Ks;
  for (int k0 = kb0; k0 < kend; k0 += 32) {
    async16(a0 + k0, lA0);
    async16(a1 + k0, lA1);
    async16(b0 + k0, lB0);
    async16(b1 + k0, lB1);
    __syncthreads();
    bf16x8 af[4], bfv[4];
    #pragma unroll
    for (int mi = 0; mi < 4; mi++)
      af[mi] = *(const bf16x8*)&As[(wm * 64 + mi * 16 + l16) * 32 + quad * 8];
    #pragma unroll
    for (int ni = 0; ni < 4; ni++)
      bfv[ni] = *(const bf16x8*)&Bs[(wn * 64 + ni * 16 + l16) * 32 + quad * 8];
    #pragma unroll
    for (int mi = 0; mi < 4; mi++)
      #pragma unroll
      for (int ni = 0; ni < 4; ni++)
        acc[mi][ni] = __builtin_amdgcn_mfma_f32_16x16x32_bf16(af[mi], bfv[ni], acc[mi][ni], 0, 0, 0);
    __syncthreads();
  }
  float* Cfo = Cf ? Cf + (size_t)blockIdx.y * MN : nullptr;
  #pragma unroll
  for (int mi = 0; mi < 4; mi++) {
    #pragma unroll
    for (int r = 0; r < 4; r++) {
      int m = bm + wm * 64 + mi * 16 + quad * 4 + r;
      if (m < M) {
        #pragma unroll
        for (int ni = 0; ni < 4; ni++) {
          int n = bn + wn * 64 + ni * 16 + l16;
          float val = acc[mi][ni][r] + (bias ? bias[n] : 0.f);
          if (act == 1) {
            float u = val + 0.044715f * val * val * val;
            float z = 1.5957691216057308f * u;
            val = val / (1.f + __expf(-z));
          }
          if (Cfo) Cfo[(size_t)m * N + n] = val;
          else     Cb[(size_t)m * N + n] = (bf16)val;
        }
      }
    }
  }
}

// ---------------- V transpose from bf16 source (bias pre-applied) ----------------
// src(l,d) = Xb[l*RS + CO + d]  ->  Vt[d * L + l]
__global__ __launch_bounds__(256)
void transposev_kernel(const bf16* __restrict__ Xb, int RS, int CO,
                       bf16* __restrict__ Vt, int L)
{
  __shared__ bf16 T[64][65];
  int l0 = blockIdx.x * 64, n0 = blockIdx.y * 64;
  int tid = threadIdx.x;
  int r = tid >> 2;
  int c8 = (tid & 3) * 16;
  int lc = l0 + r; if (lc > L - 1) lc = L - 1;
  const bf16* src = Xb + (size_t)lc * RS + CO + n0 + c8;
  #pragma unroll
  for (int i = 0; i < 16; i++) T[r][c8 + i] = src[i];
  __syncthreads();
  #pragma unroll
  for (int i = 0; i < 16; i++) {
    int l = l0 + c8 + i;
    if (l < L) Vt[(size_t)(n0 + r) * L + l] = T[c8 + i][r];
  }
}

// ---------------- flash attention v2: block-cooperative, LDS-staged ----------------
__global__ __launch_bounds__(256)
void flash2_kernel(const bf16* __restrict__ Q, const bf16* __restrict__ Kg,
                   const bf16* __restrict__ Vt, bf16* __restrict__ O,
                   int Lq, int Lk, int FS, int causal, int nqb)
{
  __shared__ bf16 Kt[64 * 128];
  __shared__ bf16 Vtile[128 * 64];
  __shared__ bf16 Pl[4][16][72];
  int tid = threadIdx.x, lane = tid & 63, w = tid >> 6;
  int l16 = lane & 15, quad = lane >> 4;
  int bid = blockIdx.x;
  int h = bid % NHEADS;
  int qb = nqb - 1 - (bid / NHEADS);
  int q0b = qb * 64;
  int q0w = q0b + w * 16;

  int qrow = q0w + l16; if (qrow > Lq - 1) qrow = Lq - 1;
  const bf16* qbase = Q + (size_t)qrow * DMODEL + h * HD + quad * 8;
  bf16x8 qf[4];
  #pragma unroll
  for (int dc = 0; dc < 4; dc++) qf[dc] = *(const bf16x8*)(qbase + dc * 32);

  int kvrow[4];
  int kvmin_w = Lk, kv_end = Lk;
  if (causal) {
    #pragma unroll
    for (int r = 0; r < 4; r++) {
      int qr = q0w + quad * 4 + r; if (qr > Lq - 1) qr = Lq - 1;
      kvrow[r] = (qr / FS + 1) * FS;
    }
    int q0c = q0w; if (q0c > Lq - 1) q0c = Lq - 1;
    kvmin_w = (q0c / FS + 1) * FS;
    int qlast = q0b + 63; if (qlast > Lq - 1) qlast = Lq - 1;
    kv_end = (qlast / FS + 1) * FS;
    if (kv_end > Lk) kv_end = Lk;
  }

  f32x4 acc_o[8] = {};
  float m_i[4], l_i[4];
  #pragma unroll
  for (int r = 0; r < 4; r++) { m_i[r] = -1e30f; l_i[r] = 0.f; }

  for (int kb = 0; kb < kv_end; kb += 64) {
    #pragma unroll
    for (int j = 0; j < 4; j++) {
      int u = w * 256 + j * 64 + lane;
      int row = u >> 4;
      int c = (u & 15) ^ (row & 15);
      int krow = kb + row; if (krow > Lk - 1) krow = Lk - 1;
      async16(Kg + (size_t)krow * DMODEL + h * HD + c * 8,
              Kt + (size_t)(w * 256 + j * 64) * 8);
    }
    #pragma unroll
    for (int j = 0; j < 4; j++) {
      int u = w * 256 + j * 64 + lane;
      int row = u >> 3;
      int c = (u & 7) ^ (row & 7);
      async16(Vt + (size_t)(h * HD + row) * Lk + kb + c * 8,
              Vtile + (size_t)(w * 256 + j * 64) * 8);
    }
    __syncthreads();

    f32x4 s[4] = {};
    #pragma unroll
    for (int nk = 0; nk < 4; nk++) {
      #pragma unroll
      for (int dc = 0; dc < 4; dc++) {
        bf16x8 kf = *(const bf16x8*)&Kt[(((nk * 16 + l16) << 4) + ((4 * dc + quad) ^ l16)) * 8];
        s[nk] = __builtin_amdgcn_mfma_f32_16x16x32_bf16(qf[dc], kf, s[nk], 0, 0, 0);
      }
    }

    bool need_mask = causal && (kb + 64 > kvmin_w);
    float p[4][4];
    #pragma unroll
    for (int r = 0; r < 4; r++) {
      #pragma unroll
      for (int nk = 0; nk < 4; nk++) {
        float sv = s[nk][r];
        if (need_mask && (kb + nk * 16 + l16 >= kvrow[r])) sv = -1e30f;
        p[nk][r] = sv;
      }
      float bm = fmaxf(fmaxf(p[0][r], p[1][r]), fmaxf(p[2][r], p[3][r]));
      #pragma unroll
      for (int off = 8; off; off >>= 1) bm = fmaxf(bm, __shfl_xor(bm, off));
      float mn = fmaxf(m_i[r], bm);
      float alpha = __expf(m_i[r] - mn);
      m_i[r] = mn;
      float ps = 0.f;
      #pragma unroll
      for (int nk = 0; nk < 4; nk++) {
        float e = __expf(p[nk][r] - mn);
        p[nk][r] = e; ps += e;
      }
      #pragma unroll
      for (int off = 8; off; off >>= 1) ps += __shfl_xor(ps, off);
      l_i[r] = l_i[r] * alpha + ps;
      #pragma unroll
      for (int t = 0; t < 8; t++) acc_o[t][r] *= alpha;
    }

    #pragma unroll
    for (int nk = 0; nk < 4; nk++)
      #pragma unroll
      for (int r = 0; r < 4; r++)
        Pl[w][quad * 4 + r][nk * 16 + l16] = (bf16)p[nk][r];
    __threadfence_block();
    bf16x8 pf0 = *(const bf16x8*)&Pl[w][l16][quad * 8];
    bf16x8 pf1 = *(const bf16x8*)&Pl[w][l16][32 + quad * 8];

    #pragma unroll
    for (int t = 0; t < 8; t++) {
      bf16x8 vf0 = *(const bf16x8*)&Vtile[(((t * 16 + l16) << 3) + ((quad) ^ (l16 & 7))) * 8];
      bf16x8 vf1 = *(const bf16x8*)&Vtile[(((t * 16 + l16) << 3) + ((4 + quad) ^ (l16 & 7))) * 8];
      acc_o[t] = __builtin_amdgcn_mfma_f32_16x16x32_bf16(pf0, vf0, acc_o[t], 0, 0, 0);
      acc_o[t] = __builtin_amdgcn_mfma_f32_16x16x32_bf16(pf1, vf1, acc_o[t], 0, 0, 0);
    }
    __syncthreads();
  }

  #pragma unroll
  for (int r = 0; r < 4; r++) {
    int m = q0w + quad * 4 + r;
    if (m < Lq) {
      float inv = 1.f / l_i[r];
      bf16* obase = O + (size_t)m * DMODEL + h * HD;
      #pragma unroll
      for (int t = 0; t < 8; t++)
        obase[t * 16 + l16] = (bf16)(acc_o[t][r] * inv);
    }
  }
}

// ---------------- elementwise (fused split-K reduce + bias) ----------------
__global__ __launch_bounds__(256)
void modresid_kernel(const float* __restrict__ base, const float* __restrict__ P,
                     int S, long long MN, const float* __restrict__ bias,
                     float* __restrict__ out,
                     const float* __restrict__ sst, const float* __restrict__ temb,
                     int jg, int FS, long long total)
{
  long long i = (long long)blockIdx.x * 256 + threadIdx.x;
  if (i >= total) return;
  int d = (int)(i % DMODEL);
  int f = (int)((i / DMODEL) / FS);
  float g = sst[jg * DMODEL + d] + temb[(f * 6 + jg) * DMODEL + d];
  float v = bias[d];
  for (int s = 0; s < S; s++) v += P[(size_t)s * MN + i];
  out[i] = base[i] + v * g;
}

__global__ __launch_bounds__(256)
void addf_kernel(float* __restrict__ h, const float* __restrict__ P,
                 int S, long long MN, const float* __restrict__ bias, long long total)
{
  long long i = (long long)blockIdx.x * 256 + threadIdx.x;
  if (i >= total) return;
  int d = (int)(i % DMODEL);
  float v = bias[d];
  for (int s = 0; s < S; s++) v += P[(size_t)s * MN + i];
  h[i] += v;
}

__global__ __launch_bounds__(256)
void cast_kernel(const float* __restrict__ x, bf16* __restrict__ y, long long total)
{
  long long i = (long long)blockIdx.x * 256 + threadIdx.x;
  if (i < total) y[i] = (bf16)x[i];
}

// ---------------- orchestration ----------------
extern "C" void kernel_launch(void* const* d_in, const int* in_sizes, int n_in,
                              void* d_out, int out_size, void* d_ws, size_t ws_size,
                              hipStream_t stream)
{
  const float* hs   = (const float*)d_in[0];
  const float* enc  = (const float*)d_in[1];
  const float* temb = (const float*)d_in[2];
  const float* cosb = (const float*)d_in[3];
  const float* sinb = (const float*)d_in[4];
  const float* sst  = (const float*)d_in[6];
  const float* wq = (const float*)d_in[7];
  const float* wk = (const float*)d_in[8];
  const float* wv = (const float*)d_in[9];
  const float* wo = (const float*)d_in[10];
  const float* bq = (const float*)d_in[11];
  const float* bk = (const float*)d_in[12];
  const float* bv = (const float*)d_in[13];
  const float* bo = (const float*)d_in[14];
  const float* nq_w = (const float*)d_in[15];
  const float* nk_w = (const float*)d_in[16];
  const float* ln2_g = (const float*)d_in[17];
  const float* ln2_b = (const float*)d_in[18];
  const float* cwq = (const float*)d_in[19];
  const float* cwk = (const float*)d_in[20];
  const float* cwv = (const float*)d_in[21];
  const float* cwo = (const float*)d_in[22];
  const float* cbq = (const float*)d_in[23];
  const float* cbk = (const float*)d_in[24];
  const float* cbv = (const float*)d_in[25];
  const float* cbo = (const float*)d_in[26];
  const float* cnq_w = (const float*)d_in[27];
  const float* cnk_w = (const float*)d_in[28];
  const float* w1 = (const float*)d_in[29];
  const float* b1 = (const float*)d_in[30];
  const float* w2 = (const float*)d_in[31];
  const float* b2 = (const float*)d_in[32];

  int L  = in_sizes[0] / DMODEL;
  int LC = in_sizes[1] / DMODEL;
  int F  = in_sizes[2] / (6 * DMODEL);
  int FS = L / F;
  int FF = in_sizes[30];
  long long LD = (long long)L * DMODEL;
  float* outp = (float*)d_out;
  int N3 = 3 * DMODEL, N2 = 2 * DMODEL;

  // ---- workspace layout with liveness-based aliasing (~248 MB total) ----
  char* p = (char*)d_ws;
  auto alloc = [&](size_t bytes) -> char* {
    char* r = p; p += (bytes + 255) & ~(size_t)255; return r;
  };
  size_t DD = (size_t)DMODEL * DMODEL;
  bf16* wqkv_t = (bf16*)alloc(DD * 3 * 2);
  bf16* wto_t  = (bf16*)alloc(DD * 2);
  bf16* cwq_t  = (bf16*)alloc(DD * 2);
  bf16* cwkv_t = (bf16*)alloc(DD * 2 * 2);
  bf16* cwo_t  = (bf16*)alloc(DD * 2);
  bf16* w1t = (bf16*)alloc((size_t)DMODEL * FF * 2);
  bf16* w2t = (bf16*)alloc((size_t)DMODEL * FF * 2);
  float* bqkv = (float*)alloc((size_t)N3 * 4);
  float* cbkv = (float*)alloc((size_t)N2 * 4);
  float* hbuf = (float*)alloc((size_t)LD * 4);
  bf16* nh   = (bf16*)alloc((size_t)LD * 2);
  bf16* qb   = (bf16*)alloc((size_t)LD * 2);
  bf16* kb   = (bf16*)alloc((size_t)LD * 2);
  bf16* ab   = (bf16*)alloc((size_t)LD * 2);
  bf16* vtc  = (bf16*)alloc((size_t)LC * DMODEL * 2);
  bf16* encb = (bf16*)alloc((size_t)LC * DMODEL * 2);
  // BIG1: phase2 qkvb (L*N3 bf16) -> phase4 ckvb (LC*N2 bf16) -> phase5 ffb (L*FF bf16)
  char* BIG1 = alloc((size_t)L * FF * 2);
  bf16* qkvb = (bf16*)BIG1;
  bf16* ckvb = (bf16*)BIG1;
  bf16* ffb  = (bf16*)BIG1;
  // BIG2: phase2-3 vtb (LD bf16) -> phase3/4/5 split-K partials Pp (2 x LD fp32)
  char* BIG2 = alloc((size_t)LD * 2 * 4);
  bf16* vtb = (bf16*)BIG2;
  float* Pp = (float*)BIG2;
  (void)ws_size; (void)n_in; (void)out_size;

  dim3 gWdd(DMODEL / 32, DMODEL / 32);
  wt_kernel<<<gWdd, 256, 0, stream>>>(wq, wqkv_t, DMODEL, DMODEL);
  wt_kernel<<<gWdd, 256, 0, stream>>>(wk, wqkv_t + DD, DMODEL, DMODEL);
  wt_kernel<<<gWdd, 256, 0, stream>>>(wv, wqkv_t + 2 * DD, DMODEL, DMODEL);
  wt_kernel<<<gWdd, 256, 0, stream>>>(wo, wto_t, DMODEL, DMODEL);
  wt_kernel<<<gWdd, 256, 0, stream>>>(cwq, cwq_t, DMODEL, DMODEL);
  wt_kernel<<<gWdd, 256, 0, stream>>>(cwk, cwkv_t, DMODEL, DMODEL);
  wt_kernel<<<gWdd, 256, 0, stream>>>(cwv, cwkv_t + DD, DMODEL, DMODEL);
  wt_kernel<<<gWdd, 256, 0, stream>>>(cwo, cwo_t, DMODEL, DMODEL);
  wt_kernel<<<dim3(DMODEL / 32, FF / 32), 256, 0, stream>>>(w1, w1t, DMODEL, FF);
  wt_kernel<<<dim3(FF / 32, DMODEL / 32), 256, 0, stream>>>(w2, w2t, FF, DMODEL);
  catbias_kernel<<<6, 256, 0, stream>>>(bqkv, bq, bk, bv, cbkv, cbk, cbv);

  int gxL = (L + 127) / 128, gxC = (LC + 127) / 128;
  int ewg = (int)((LD + 255) / 256);
  int nqb = (L + 63) / 64;
  const float qs = 0.08838834764831845f;  // 1/sqrt(128)

  // 1) AdaLN-modulated LN of hidden
  ln_kernel<<<L, 256, 0, stream>>>(hs, nh, sst, temb, nullptr, nullptr, 0, 1, FS, 0);
  // 2) fused q/k/v projection, bf16 out with fused bias
  gemm_bt<<<dim3(gxL * (N3 / 128), 1), 256, 0, stream>>>(nh, wqkv_t, bqkv, nullptr, qkvb,
                                                         L, N3, DMODEL, 0, DMODEL, 0);
  rms_rope_kernel<<<L, 256, 0, stream>>>(nullptr, 0, 0, qkvb, N3, 0, nullptr, qb, nq_w, cosb, sinb, 1, qs);
  rms_rope_kernel<<<L, 256, 0, stream>>>(nullptr, 0, 0, qkvb, N3, DMODEL, nullptr, kb, nk_w, cosb, sinb, 1, 1.0f);
  transposev_kernel<<<dim3((L + 63) / 64, DMODEL / 64), 256, 0, stream>>>(qkvb, N3, 2 * DMODEL, vtb, L);
  // 3) self attention (block-causal)
  flash2_kernel<<<NHEADS * nqb, 256, 0, stream>>>(qb, kb, vtb, ab, L, L, FS, 1, nqb);
  gemm_bt<<<dim3(gxL * (DMODEL / 128), 2), 256, 0, stream>>>(ab, wto_t, nullptr, Pp, nullptr,
                                                             L, DMODEL, DMODEL, 0, DMODEL / 2, LD);
  modresid_kernel<<<ewg, 256, 0, stream>>>(hs, Pp, 2, LD, bo, hbuf, sst, temb, 2, FS, LD);
  // 4) cross attention
  ln_kernel<<<L, 256, 0, stream>>>(hbuf, nh, nullptr, nullptr, ln2_g, ln2_b, 0, 0, FS, 1);
  gemm_bt<<<dim3(gxL * (DMODEL / 128), 2), 256, 0, stream>>>(nh, cwq_t, nullptr, Pp, nullptr,
                                                             L, DMODEL, DMODEL, 0, DMODEL / 2, LD);
  rms_rope_kernel<<<L, 256, 0, stream>>>(Pp, 2, LD, nullptr, DMODEL, 0, cbq, qb, cnq_w, nullptr, nullptr, 0, qs);
  cast_kernel<<<(int)(((long long)LC * DMODEL + 255) / 256), 256, 0, stream>>>(enc, encb, (long long)LC * DMODEL);
  gemm_bt<<<dim3(gxC * (N2 / 128), 1), 256, 0, stream>>>(encb, cwkv_t, cbkv, nullptr, ckvb,
                                                         LC, N2, DMODEL, 0, DMODEL, 0);
  rms_rope_kernel<<<LC, 256, 0, stream>>>(nullptr, 0, 0, ckvb, N2, 0, nullptr, kb, cnk_w, nullptr, nullptr, 0, 1.0f);
  transposev_kernel<<<dim3((LC + 63) / 64, DMODEL / 64), 256, 0, stream>>>(ckvb, N2, DMODEL, vtc, LC);
  flash2_kernel<<<NHEADS * nqb, 256, 0, stream>>>(qb, kb, vtc, ab, L, LC, FS, 0, nqb);
  gemm_bt<<<dim3(gxL * (DMODEL / 128), 2), 256, 0, stream>>>(ab, cwo_t, nullptr, Pp, nullptr,
                                                             L, DMODEL, DMODEL, 0, DMODEL / 2, LD);
  addf_kernel<<<ewg, 256, 0, stream>>>(hbuf, Pp, 2, LD, cbo, LD);
  // 5) FFN
  ln_kernel<<<L, 256, 0, stream>>>(hbuf, nh, sst, temb, nullptr, nullptr, 3, 4, FS, 0);
  gemm_bt<<<dim3(gxL * (FF / 128), 1), 256, 0, stream>>>(nh, w1t, b1, nullptr, ffb,
                                                         L, FF, DMODEL, 1, DMODEL, 0);
  gemm_bt<<<dim3(gxL * (DMODEL / 128), 2), 256, 0, stream>>>(ffb, w2t, nullptr, Pp, nullptr,
                                                             L, DMODEL, FF, 0, FF / 2, LD);
  modresid_kernel<<<ewg, 256, 0, stream>>>(hbuf, Pp, 2, LD, b2, outp, sst, temb, 5, FS, LD);
}